// Round 1
// baseline (2223.990 us; speedup 1.0000x reference)
//
#include <hip/hip_runtime.h>
#include <cstdint>
#include <cstddef>

#define N_PTS 65536
#define B_SZ 32
#define K_FPS 8
#define GRP 512
#define NP 513          // GRP + 1 points per group
#define HD 128
#define R2C 0.04f
#define BIGF 1e10f

// ---------------------------------------------------------------------------
// FPS: one block per batch, sequential 8-step farthest point sampling.
// Matches jax.lax.scan semantics: cents = [0, a1..a7], a_i = argmax (first
// index on tie) of running min-distance after updates with centers f0..f_{i-1}.
// ---------------------------------------------------------------------------
__global__ __launch_bounds__(1024) void fps_kernel(const float* __restrict__ x,
                                                   float* __restrict__ dist,
                                                   int* __restrict__ cents) {
  int b = blockIdx.x;
  int tid = threadIdx.x;
  const float* xb = x + (size_t)b * N_PTS * 3;
  float* db = dist + (size_t)b * N_PTS;
  __shared__ float rv[1024];
  __shared__ int ri[1024];
  __shared__ int s_far;
  if (tid == 0) s_far = 0;
  __syncthreads();
  for (int it = 0; it < K_FPS; ++it) {
    int far = s_far;
    if (tid == 0) cents[b * K_FPS + it] = far;
    float c0 = xb[far * 3 + 0], c1 = xb[far * 3 + 1], c2 = xb[far * 3 + 2];
    float best = -1.0f;
    int bidx = 0;
    for (int i = tid; i < N_PTS; i += 1024) {
      float dx = xb[i * 3 + 0] - c0;
      float dy = xb[i * 3 + 1] - c1;
      float dz = xb[i * 3 + 2] - c2;
      float d = dx * dx + dy * dy + dz * dz;
      float old;
      if (it == 0) old = BIGF; else old = db[i];
      float nd = fminf(old, d);
      db[i] = nd;
      if (nd > best) { best = nd; bidx = i; }   // strict > keeps first index
    }
    rv[tid] = best; ri[tid] = bidx;
    __syncthreads();
    for (int s = 512; s > 0; s >>= 1) {
      if (tid < s) {
        float v2 = rv[tid + s]; int i2 = ri[tid + s];
        if (v2 > rv[tid] || (v2 == rv[tid] && i2 < ri[tid])) { rv[tid] = v2; ri[tid] = i2; }
      }
      __syncthreads();
    }
    if (tid == 0) s_far = ri[0];
    __syncthreads();
  }
}

// ---------------------------------------------------------------------------
// Ball query + grouping. One block per (b,k) group. Builds (in index order)
// the list of in-radius points and the list of out-of-radius points (fill),
// then writes combined points: slot 0 = centroid abs coords, 1..512 = rel.
// Downstream is permutation invariant, so only the SET matters; stable
// argsort of [masked dists] == all-in-radius + lowest-index fills when
// in-count <= 512 (true for this data: max ~200).
// ---------------------------------------------------------------------------
__global__ __launch_bounds__(256) void ballq_kernel(const float* __restrict__ x,
                                                    const int* __restrict__ cents,
                                                    float* __restrict__ cxyz,
                                                    float* __restrict__ grouped) {
  int g = blockIdx.x;           // 0..255  (b*8 + k)
  int b = g >> 3;
  int tid = threadIdx.x;        // 256
  __shared__ int s_in[GRP];
  __shared__ int s_out[GRP];
  __shared__ int s_cnt[2];
  __shared__ int warp_tot[2][4];
  __shared__ float sc[3];
  const float* xb = x + (size_t)b * N_PTS * 3;
  if (tid == 0) {
    int ci = cents[g];
    sc[0] = xb[ci * 3 + 0]; sc[1] = xb[ci * 3 + 1]; sc[2] = xb[ci * 3 + 2];
    s_cnt[0] = 0; s_cnt[1] = 0;
  }
  __syncthreads();
  float c0 = sc[0], c1 = sc[1], c2 = sc[2];
  int lane = tid & 63, wid = tid >> 6;
  unsigned long long lanemask = (1ull << lane) - 1ull;
  for (int base = 0; base < N_PTS; base += 256) {
    int i = base + tid;
    float dx = xb[i * 3 + 0] - c0;
    float dy = xb[i * 3 + 1] - c1;
    float dz = xb[i * 3 + 2] - c2;
    float d = dx * dx + dy * dy + dz * dz;
    bool inr = !(d > R2C);
    unsigned long long mi = __ballot(inr);
    int bin = s_cnt[0], bout = s_cnt[1];       // stable since last sync
    if (lane == 0) {
      warp_tot[0][wid] = __popcll(mi);
      warp_tot[1][wid] = 64 - __popcll(mi);
    }
    __syncthreads();
    int pin = __popcll(mi & lanemask);
    int pout = lane - pin;
    for (int w = 0; w < wid; ++w) { pin += warp_tot[0][w]; pout += warp_tot[1][w]; }
    if (inr) { int p = bin + pin; if (p < GRP) s_in[p] = i; }
    else     { int p = bout + pout; if (p < GRP) s_out[p] = i; }
    __syncthreads();
    if (tid == 0) {
      int ti = warp_tot[0][0] + warp_tot[0][1] + warp_tot[0][2] + warp_tot[0][3];
      s_cnt[0] = bin + ti;
      s_cnt[1] = bout + (256 - ti);
    }
    __syncthreads();
  }
  int incnt = min(s_cnt[0], GRP);
  if (tid == 0) {
    cxyz[g * 3 + 0] = c0; cxyz[g * 3 + 1] = c1; cxyz[g * 3 + 2] = c2;
    float* o0 = grouped + (size_t)g * NP * 3;
    o0[0] = c0; o0[1] = c1; o0[2] = c2;     // slot 0: absolute centroid
  }
  __syncthreads();
  for (int j = tid; j < GRP; j += 256) {
    int src = (j < incnt) ? s_in[j] : s_out[j - incnt];
    float* o = grouped + ((size_t)g * NP + 1 + j) * 3;
    o[0] = xb[src * 3 + 0] - c0;
    o[1] = xb[src * 3 + 1] - c1;
    o[2] = xb[src * 3 + 2] - c2;
  }
}

// ---------------------------------------------------------------------------
// conv_in: y[r][c] = relu(b[c] + sum_j gp[r][j]*W[c][j]), W is [128][3]
// ---------------------------------------------------------------------------
__global__ void conv_in_kernel(const float* __restrict__ gp,
                               const float* __restrict__ W,
                               const float* __restrict__ bias,
                               float* __restrict__ y, int M) {
  int idx = blockIdx.x * blockDim.x + threadIdx.x;
  if (idx >= M * HD) return;
  int r = idx >> 7, c = idx & 127;
  const float* p = gp + (size_t)r * 3;
  float v = bias[c] + p[0] * W[c * 3 + 0] + p[1] * W[c * 3 + 1] + p[2] * W[c * 3 + 2];
  y[idx] = fmaxf(v, 0.0f);
}

// ---------------------------------------------------------------------------
// GEMM: C[M][128] = f( A[M][128] @ W^T )  where W row = W + c*wstride + wcol.
// 128x128 tile, 512 threads, thread = 4 rows x 8 cols.
// BIAS_MODE: 0 none, 1 per-channel bias[c], 2 per-group bias[row/513][c]
// ---------------------------------------------------------------------------
template <int BIAS_MODE, bool RELU, bool ACCUM>
__global__ __launch_bounds__(512, 1) void gemm128(const float* __restrict__ A,
                                                  const float* __restrict__ W,
                                                  int wstride, int wcol,
                                                  const float* __restrict__ bias,
                                                  float* __restrict__ C, int M) {
  __shared__ float As[128][132];
  __shared__ float Ws[128][132];
  int tid = threadIdx.x;
  int m0 = blockIdx.x * 128;
#pragma unroll
  for (int q = 0; q < 8; ++q) {
    int e = (tid + 512 * q) * 4;
    int r = e >> 7, c = e & 127;
    const float* src = W + (size_t)r * wstride + wcol + c;
    float4 v = *(const float4*)src;
    *(float4*)&Ws[r][c] = v;
  }
#pragma unroll
  for (int q = 0; q < 8; ++q) {
    int e = (tid + 512 * q) * 4;
    int r = e >> 7, c = e & 127;
    int row = m0 + r;
    float4 v = {0.f, 0.f, 0.f, 0.f};
    if (row < M) v = *(const float4*)(A + (size_t)row * HD + c);
    *(float4*)&As[r][c] = v;
  }
  __syncthreads();
  int tx = tid & 15, ty = tid >> 4;     // tx: col group (16), ty: row group (32)
  float acc[4][8];
#pragma unroll
  for (int i = 0; i < 4; ++i)
#pragma unroll
    for (int j = 0; j < 8; ++j) acc[i][j] = 0.0f;

  for (int k = 0; k < 128; k += 4) {
    float4 a[4];
#pragma unroll
    for (int i = 0; i < 4; ++i) a[i] = *(const float4*)&As[ty * 4 + i][k];
#pragma unroll
    for (int j = 0; j < 8; ++j) {
      float4 w = *(const float4*)&Ws[tx + 16 * j][k];
#pragma unroll
      for (int i = 0; i < 4; ++i) {
        acc[i][j] += a[i].x * w.x;
        acc[i][j] += a[i].y * w.y;
        acc[i][j] += a[i].z * w.z;
        acc[i][j] += a[i].w * w.w;
      }
    }
  }
#pragma unroll
  for (int i = 0; i < 4; ++i) {
    int row = m0 + ty * 4 + i;
    if (row >= M) break;
    float* crow = C + (size_t)row * HD;
    int grp = row / NP;
#pragma unroll
    for (int j = 0; j < 8; ++j) {
      int col = tx + 16 * j;
      float v = acc[i][j];
      if (BIAS_MODE == 1) v += bias[col];
      if (BIAS_MODE == 2) v += bias[grp * HD + col];
      if (ACCUM) v += crow[col];
      if (RELU) v = fmaxf(v, 0.0f);
      crow[col] = v;
    }
  }
}

// ---------------------------------------------------------------------------
// Per-group max over 513 points: tmax[g][c] = max_p t[g*513+p][c]
// ---------------------------------------------------------------------------
__global__ void maxred_kernel(const float* __restrict__ t, float* __restrict__ tmax) {
  int g = blockIdx.x, c = threadIdx.x;   // 128 threads
  const float* base = t + (size_t)g * NP * HD + c;
  float m = -1e30f;
  for (int p = 0; p < NP; ++p) m = fmaxf(m, base[(size_t)p * HD]);
  tmax[g * HD + c] = m;
}

// gvec[g][c] = gb[c] + sum_k tmax[g][k] * gw[c][128+k]   (gw is [128][256])
__global__ void gvec_kernel(const float* __restrict__ tmax, const float* __restrict__ gw,
                            const float* __restrict__ gb, float* __restrict__ gvec) {
  int g = blockIdx.x, c = threadIdx.x;   // 128 threads
  __shared__ float sm[HD];
  sm[c] = tmax[g * HD + c];
  __syncthreads();
  const float* wr = gw + (size_t)c * (2 * HD) + HD;
  float s = gb[c];
  for (int j = 0; j < HD; ++j) s += sm[j] * wr[j];
  gvec[g * HD + c] = s;
}

// gout[g][c] = max_p acc[g*513+p][c] + bout[c]
__global__ void groupout_kernel(const float* __restrict__ acc, const float* __restrict__ bout,
                                float* __restrict__ gout) {
  int g = blockIdx.x, c = threadIdx.x;   // 128 threads
  const float* base = acc + (size_t)g * NP * HD + c;
  float m = -1e30f;
  for (int p = 0; p < NP; ++p) m = fmaxf(m, base[(size_t)p * HD]);
  gout[g * HD + c] = m + bout[c];
}

// y_global[b][c] = max_k gout[b*8+k][c]
__global__ void batchmax_kernel(const float* __restrict__ gout, float* __restrict__ out) {
  int b = blockIdx.x, c = threadIdx.x;   // 128 threads
  float m = -1e30f;
  for (int k = 0; k < K_FPS; ++k) m = fmaxf(m, gout[(size_t)(b * K_FPS + k) * HD + c]);
  out[b * HD + c] = m;
}

// ---------------------------------------------------------------------------
// Centroid MLP path, one block per batch. LN with two-pass mean/var.
// ---------------------------------------------------------------------------
__device__ __forceinline__ void block_ln(float* h, int n, const float* __restrict__ gam,
                                         const float* __restrict__ bet, float* red,
                                         int tid, bool relu) {
  float v = (tid < n) ? h[tid] : 0.0f;
  red[tid] = v;
  __syncthreads();
  for (int s = 128; s > 0; s >>= 1) { if (tid < s) red[tid] += red[tid + s]; __syncthreads(); }
  float mean = red[0] / n;
  __syncthreads();
  float d = (tid < n) ? (h[tid] - mean) : 0.0f;
  red[tid] = d * d;
  __syncthreads();
  for (int s = 128; s > 0; s >>= 1) { if (tid < s) red[tid] += red[tid + s]; __syncthreads(); }
  float var = red[0] / n;
  __syncthreads();
  if (tid < n) {
    float o = (h[tid] - mean) / sqrtf(var + 1e-5f) * gam[tid] + bet[tid];
    if (relu) o = fmaxf(o, 0.0f);
    h[tid] = o;
  }
  __syncthreads();
}

__global__ __launch_bounds__(256) void cpath_kernel(const float* __restrict__ cxyz,
    const float* __restrict__ w0, const float* __restrict__ b0,
    const float* __restrict__ g0, const float* __restrict__ e0,
    const float* __restrict__ w1, const float* __restrict__ b1,
    const float* __restrict__ g1, const float* __restrict__ e1,
    const float* __restrict__ w2, const float* __restrict__ b2,
    const float* __restrict__ g2, const float* __restrict__ e2,
    const float* __restrict__ fw, const float* __restrict__ fb,
    const float* __restrict__ fg, const float* __restrict__ fe,
    float* __restrict__ out) {
  int b = blockIdx.x, tid = threadIdx.x;   // 256 threads
  __shared__ float h[256];
  __shared__ float hb[256];
  __shared__ float cmax[256];
  __shared__ float red[256];
  cmax[tid] = -1e30f;
  __syncthreads();
  for (int k = 0; k < K_FPS; ++k) {
    const float* cp = cxyz + (size_t)(b * K_FPS + k) * 3;
    float p0 = cp[0], p1 = cp[1], p2 = cp[2];
    if (tid < 64)
      h[tid] = b0[tid] + p0 * w0[tid * 3 + 0] + p1 * w0[tid * 3 + 1] + p2 * w0[tid * 3 + 2];
    __syncthreads();
    block_ln(h, 64, g0, e0, red, tid, true);
    if (tid < 128) {
      float s = b1[tid];
      const float* wr = w1 + (size_t)tid * 64;
      for (int j = 0; j < 64; ++j) s += h[j] * wr[j];
      hb[tid] = s;
    }
    __syncthreads();
    block_ln(hb, 128, g1, e1, red, tid, true);
    {
      float s = b2[tid];
      const float* wr = w2 + (size_t)tid * 128;
      for (int j = 0; j < 128; ++j) s += hb[j] * wr[j];
      __syncthreads();
      h[tid] = s;
    }
    __syncthreads();
    block_ln(h, 256, g2, e2, red, tid, true);
    cmax[tid] = fmaxf(cmax[tid], h[tid]);
    __syncthreads();
  }
  if (tid < 128) {
    float s = fb[tid];
    const float* wr = fw + (size_t)tid * 256;
    for (int j = 0; j < 256; ++j) s += cmax[j] * wr[j];
    h[tid] = s;
  }
  __syncthreads();
  block_ln(h, 128, fg, fe, red, tid, false);
  if (tid < 128) out[b * HD + tid] = h[tid];
}

// ---------------------------------------------------------------------------
extern "C" void kernel_launch(void* const* d_in, const int* in_sizes, int n_in,
                              void* d_out, int out_size, void* d_ws, size_t ws_size,
                              hipStream_t stream) {
  (void)in_sizes; (void)n_in; (void)out_size;
  const float* x          = (const float*)d_in[0];
  const float* conv_in_w  = (const float*)d_in[1];
  const float* conv_in_b  = (const float*)d_in[2];
  const float* layer_w    = (const float*)d_in[3];
  const float* layer_b    = (const float*)d_in[4];
  const float* glayer_w   = (const float*)d_in[5];
  const float* glayer_b   = (const float*)d_in[6];
  const float* conv_out_w = (const float*)d_in[7];
  const float* conv_out_b = (const float*)d_in[8];
  const float* mlp_w0 = (const float*)d_in[9];
  const float* mlp_b0 = (const float*)d_in[10];
  const float* ln0_g  = (const float*)d_in[11];
  const float* ln0_b  = (const float*)d_in[12];
  const float* mlp_w1 = (const float*)d_in[13];
  const float* mlp_b1 = (const float*)d_in[14];
  const float* ln1_g  = (const float*)d_in[15];
  const float* ln1_b  = (const float*)d_in[16];
  const float* mlp_w2 = (const float*)d_in[17];
  const float* mlp_b2 = (const float*)d_in[18];
  const float* ln2_g  = (const float*)d_in[19];
  const float* ln2_b  = (const float*)d_in[20];
  const float* fp_w   = (const float*)d_in[21];
  const float* fp_b   = (const float*)d_in[22];
  const float* fp_ln_g = (const float*)d_in[23];
  const float* fp_ln_b = (const float*)d_in[24];

  char* ws = (char*)d_ws;
  size_t off = 0;
  auto carve = [&](size_t bytes) -> void* {
    void* p = ws + off;
    off += (bytes + 255) & ~(size_t)255;
    return p;
  };
  float* fps_dist = (float*)carve((size_t)B_SZ * N_PTS * 4);
  int* cents      = (int*)carve(256 * 4);
  float* cxyz     = (float*)carve(256 * 3 * 4);
  float* grouped  = (float*)carve((size_t)256 * NP * 3 * 4);
  float* gout     = (float*)carve(256 * HD * 4);
  float* tmax     = (float*)carve(256 * HD * 4);
  float* gvec     = (float*)carve(256 * HD * 4);
  size_t fixed = off;

  int C = 8;
  const int cands[6] = {256, 128, 64, 32, 16, 8};
  for (int ci = 0; ci < 6; ++ci) {
    size_t need = fixed + 3ull * cands[ci] * NP * HD * 4 + 4096;
    if (need <= ws_size) { C = cands[ci]; break; }
  }
  size_t bufsz = (size_t)C * NP * HD * 4;
  float* yb   = (float*)carve(bufsz);
  float* tb   = (float*)carve(bufsz);
  float* accb = (float*)carve(bufsz);

  fps_kernel<<<B_SZ, 1024, 0, stream>>>(x, fps_dist, cents);
  ballq_kernel<<<256, 256, 0, stream>>>(x, cents, cxyz, grouped);

  for (int g0 = 0; g0 < 256; g0 += C) {
    int M = C * NP;
    int nb = (M + 127) / 128;
    conv_in_kernel<<<(M * HD + 255) / 256, 256, 0, stream>>>(
        grouped + (size_t)g0 * NP * 3, conv_in_w, conv_in_b, yb, M);
    for (int l = 0; l < 4; ++l) {
      gemm128<1, true, false><<<nb, 512, 0, stream>>>(
          yb, layer_w + (size_t)l * HD * HD, HD, 0, layer_b + l * HD, tb, M);
      maxred_kernel<<<C, HD, 0, stream>>>(tb, tmax);
      gvec_kernel<<<C, HD, 0, stream>>>(tmax, glayer_w + (size_t)l * HD * 2 * HD,
                                        glayer_b + l * HD, gvec);
      gemm128<2, true, false><<<nb, 512, 0, stream>>>(
          tb, glayer_w + (size_t)l * HD * 2 * HD, 2 * HD, 0, gvec, yb, M);
      if (l == 0)
        gemm128<0, false, false><<<nb, 512, 0, stream>>>(
            yb, conv_out_w, 4 * HD, l * HD, nullptr, accb, M);
      else
        gemm128<0, false, true><<<nb, 512, 0, stream>>>(
            yb, conv_out_w, 4 * HD, l * HD, nullptr, accb, M);
    }
    groupout_kernel<<<C, HD, 0, stream>>>(accb, conv_out_b, gout + (size_t)g0 * HD);
  }
  batchmax_kernel<<<B_SZ, HD, 0, stream>>>(gout, (float*)d_out);
  cpath_kernel<<<B_SZ, 256, 0, stream>>>(cxyz,
      mlp_w0, mlp_b0, ln0_g, ln0_b,
      mlp_w1, mlp_b1, ln1_g, ln1_b,
      mlp_w2, mlp_b2, ln2_g, ln2_b,
      fp_w, fp_b, fp_ln_g, fp_ln_b,
      (float*)d_out + B_SZ * HD);
}

// Round 2
// 1146.513 us; speedup vs baseline: 1.9398x; 1.9398x over previous
//
#include <hip/hip_runtime.h>
#include <cstdint>
#include <cstddef>

#define N_PTS 65536
#define B_SZ 32
#define K_FPS 8
#define GRP 512
#define NP 513
#define HD 128
#define R2C 0.04f
#define BIGF 1e10f

typedef unsigned int u32;
using bf8  = __attribute__((ext_vector_type(8))) short;   // 8 x bf16 bits
using f32x4 = __attribute__((ext_vector_type(4))) float;

// ---- helpers ---------------------------------------------------------------
__device__ __forceinline__ unsigned short f2bf(float f) {
  u32 u = __float_as_uint(f);
  u32 r = (u + 0x7FFFu + ((u >> 16) & 1u)) >> 16;   // RNE
  return (unsigned short)r;
}
__device__ __forceinline__ float bf2f(unsigned short h) {
  return __uint_as_float(((u32)h) << 16);
}
// monotone float<->uint for atomicMax
__device__ __forceinline__ u32 xf(float v) {
  u32 u = __float_as_uint(v);
  return (u & 0x80000000u) ? ~u : (u | 0x80000000u);
}
__device__ __forceinline__ float xinv(u32 u) {
  return (u & 0x80000000u) ? __uint_as_float(u & 0x7FFFFFFFu) : __uint_as_float(~u);
}
__device__ __forceinline__ f32x4 mfma16(bf8 a, bf8 b, f32x4 c) {
  return __builtin_amdgcn_mfma_f32_16x16x32_bf16(a, b, c, 0, 0, 0);
}

// ---------------------------------------------------------------------------
// FPS: one block/batch, distances resident in 64 VGPRs per thread.
// ---------------------------------------------------------------------------
__global__ __launch_bounds__(1024) void fps_kernel(const float* __restrict__ x,
                                                   int* __restrict__ cents) {
  int b = blockIdx.x, tid = threadIdx.x;
  const float* xb = x + (size_t)b * N_PTS * 3;
  float dreg[64];
#pragma unroll
  for (int j = 0; j < 64; ++j) dreg[j] = BIGF;
  __shared__ float swv[16];
  __shared__ int swi[16];
  __shared__ int sfar;
  if (tid == 0) sfar = 0;
  __syncthreads();
  for (int it = 0; it < K_FPS; ++it) {
    int far = sfar;
    if (tid == 0) cents[b * K_FPS + it] = far;
    float c0 = xb[far * 3 + 0], c1 = xb[far * 3 + 1], c2 = xb[far * 3 + 2];
    float best = -1.0f; int bi = 0;
#pragma unroll
    for (int j = 0; j < 64; ++j) {
      int i = j * 1024 + tid;
      float dx = xb[i * 3 + 0] - c0;
      float dy = xb[i * 3 + 1] - c1;
      float dz = xb[i * 3 + 2] - c2;
      float d = dx * dx + dy * dy + dz * dz;
      float nd = fminf(dreg[j], d);
      dreg[j] = nd;
      if (nd > best) { best = nd; bi = i; }
    }
    // wave64 reduce (argmax, first-index tie-break)
    for (int off = 32; off > 0; off >>= 1) {
      float ov = __shfl_down(best, off);
      int oi = __shfl_down(bi, off);
      if (ov > best || (ov == best && oi < bi)) { best = ov; bi = oi; }
    }
    if ((tid & 63) == 0) { swv[tid >> 6] = best; swi[tid >> 6] = bi; }
    __syncthreads();
    if (tid == 0) {
      float bv = swv[0]; int bx = swi[0];
      for (int k = 1; k < 16; ++k)
        if (swv[k] > bv || (swv[k] == bv && swi[k] < bx)) { bv = swv[k]; bx = swi[k]; }
      sfar = bx;
    }
    __syncthreads();
  }
}

// ---------------------------------------------------------------------------
// Ball query: 1024 threads, contiguous 64-pt range per thread, bitmask + scan.
// ---------------------------------------------------------------------------
__global__ __launch_bounds__(1024) void ballq_kernel(const float* __restrict__ x,
                                                     const int* __restrict__ cents,
                                                     float* __restrict__ cxyz,
                                                     float* __restrict__ grouped) {
  int g = blockIdx.x, b = g >> 3, tid = threadIdx.x;
  const float* xb = x + (size_t)b * N_PTS * 3;
  __shared__ unsigned long long sBm[1024];
  __shared__ int sPref[1024];
  __shared__ int s_in[GRP];
  __shared__ int s_out[GRP];
  __shared__ float sc[3];
  if (tid == 0) {
    int ci = cents[g];
    sc[0] = xb[ci * 3 + 0]; sc[1] = xb[ci * 3 + 1]; sc[2] = xb[ci * 3 + 2];
  }
  __syncthreads();
  float c0 = sc[0], c1 = sc[1], c2 = sc[2];
  int base = tid * 64;
  unsigned long long bm = 0ull;
  int cnt = 0;
  for (int j = 0; j < 64; ++j) {
    int i = base + j;
    float dx = xb[i * 3 + 0] - c0;
    float dy = xb[i * 3 + 1] - c1;
    float dz = xb[i * 3 + 2] - c2;
    float d = dx * dx + dy * dy + dz * dz;
    bool inr = !(d > R2C);
    if (inr) { bm |= (1ull << j); ++cnt; }
  }
  sBm[tid] = bm;
  sPref[tid] = cnt;
  __syncthreads();
  for (int off = 1; off < 1024; off <<= 1) {
    int add = (tid >= off) ? sPref[tid - off] : 0;
    __syncthreads();
    sPref[tid] += add;
    __syncthreads();
  }
  int inc = sPref[tid];
  int exc = inc - cnt;
  int outExc = base - exc;        // exclusive prefix of out-points
  if (cnt > 0 || outExc < GRP) {
    int ii = exc, oo = outExc;
    for (int j = 0; j < 64; ++j) {
      if ((bm >> j) & 1ull) { if (ii < GRP) s_in[ii] = base + j; ++ii; }
      else                  { if (oo < GRP) s_out[oo] = base + j; ++oo; }
    }
  }
  __syncthreads();
  int incnt = min(sPref[1023], GRP);
  if (tid == 0) {
    cxyz[g * 3 + 0] = c0; cxyz[g * 3 + 1] = c1; cxyz[g * 3 + 2] = c2;
    float* o0 = grouped + (size_t)g * NP * 3;
    o0[0] = c0; o0[1] = c1; o0[2] = c2;
  } else if (tid <= GRP) {
    int j = tid - 1;
    int src = (j < incnt) ? s_in[j] : s_out[j - incnt];
    float* o = grouped + ((size_t)g * NP + 1 + j) * 3;
    o[0] = xb[src * 3 + 0] - c0;
    o[1] = xb[src * 3 + 1] - c1;
    o[2] = xb[src * 3 + 2] - c2;
  }
}

// ---------------------------------------------------------------------------
// Weight prep: fp32 -> swizzled bf16 hi/lo planes.
// layout: plane[o][k ^ ((o&7)<<3)]
// ---------------------------------------------------------------------------
__global__ void wprep_kernel(const float* __restrict__ layer_w,
                             const float* __restrict__ glayer_w,
                             const float* __restrict__ conv_out_w,
                             short* __restrict__ w1h, short* __restrict__ w1l,
                             short* __restrict__ w2h, short* __restrict__ w2l,
                             short* __restrict__ coh, short* __restrict__ col_) {
  int id = blockIdx.x * blockDim.x + threadIdx.x;
  float v; short *dh, *dl; size_t dpos;
  if (id < 65536) {
    int l = id >> 14, o = (id >> 7) & 127, k = id & 127;
    v = layer_w[(size_t)l * 16384 + o * 128 + k];
    dpos = (size_t)l * 16384 + o * 128 + (k ^ ((o & 7) << 3));
    dh = w1h; dl = w1l;
  } else if (id < 131072) {
    int t = id - 65536;
    int l = t >> 14, o = (t >> 7) & 127, k = t & 127;
    v = glayer_w[(size_t)l * 32768 + o * 256 + k];
    dpos = (size_t)l * 16384 + o * 128 + (k ^ ((o & 7) << 3));
    dh = w2h; dl = w2l;
  } else if (id < 196608) {
    int t = id - 131072;
    int o = t >> 9, k = t & 511;
    v = conv_out_w[(size_t)o * 512 + k];
    dpos = (size_t)o * 512 + (k ^ ((o & 7) << 3));
    dh = coh; dl = col_;
  } else return;
  unsigned short h = f2bf(v);
  dh[dpos] = (short)h;
  dl[dpos] = (short)f2bf(v - bf2f(h));
}

// ---------------------------------------------------------------------------
// conv_in -> y0 planes (swizzled hi/lo), pad rows zeroed.
// ---------------------------------------------------------------------------
__global__ void conv_in_kernel(const float* __restrict__ gp,
                               const float* __restrict__ W,
                               const float* __restrict__ bias,
                               short* __restrict__ oh, short* __restrict__ ol,
                               int M, int Mp) {
  int idx = blockIdx.x * blockDim.x + threadIdx.x;
  if (idx >= Mp * HD) return;
  int r = idx >> 7, c = idx & 127;
  float v = 0.0f;
  if (r < M) {
    const float* p = gp + (size_t)r * 3;
    v = bias[c] + p[0] * W[c * 3 + 0] + p[1] * W[c * 3 + 1] + p[2] * W[c * 3 + 2];
    v = fmaxf(v, 0.0f);
  }
  unsigned short h = f2bf(v);
  size_t pos = (size_t)r * HD + (c ^ ((r & 7) << 3));
  oh[pos] = (short)h;
  ol[pos] = (short)f2bf(v - bf2f(h));
}

__global__ void initu_kernel(u32* p, int n, u32 v) {
  int i = blockIdx.x * blockDim.x + threadIdx.x;
  if (i < n) p[i] = v;
}

// ---------------------------------------------------------------------------
// bf16x3-split MFMA GEMM.  out[M][128] = f(A[M][128] @ W^T)
// MODE 0: +bias[col], relu, write planes, atomicMax tmaxU[grp][col]
// MODE 1: +gvec[grp][col], relu, write planes
// MODE 2: K=512 over 4 feat buffers, no bias/relu, atomicMax goutU[grp][col]
// LDS: Ah/Al/Wh/Wl tiles 128x128 bf16 each (128 KiB). Swizzle baked in data.
// ---------------------------------------------------------------------------
template <int MODE>
__global__ __launch_bounds__(512, 2) void mfgemm(
    const short* __restrict__ a0h, const short* __restrict__ a0l,
    const short* __restrict__ a1h, const short* __restrict__ a1l,
    const short* __restrict__ a2h, const short* __restrict__ a2l,
    const short* __restrict__ a3h, const short* __restrict__ a3l,
    const short* __restrict__ wh, const short* __restrict__ wl,
    int wRowShorts,
    const float* __restrict__ bias,
    short* __restrict__ oh, short* __restrict__ ol,
    u32* __restrict__ redU,
    int M) {
  __shared__ short lds[4][128][128];
  const int tid = threadIdx.x;
  const int lane = tid & 63, w = tid >> 6;
  const int wr = w >> 2, wc = w & 3;     // 2 row-halves x 4 col-quarters
  const int m0 = blockIdx.x * 128;

  f32x4 acc[4][2];
#pragma unroll
  for (int i = 0; i < 4; ++i)
#pragma unroll
    for (int j = 0; j < 2; ++j) acc[i][j] = (f32x4){0.f, 0.f, 0.f, 0.f};

  const int NT = (MODE == 2) ? 4 : 1;
  const short* ahp[4] = {a0h, a1h, a2h, a3h};
  const short* alp[4] = {a0l, a1l, a2l, a3l};

  for (int kt = 0; kt < NT; ++kt) {
    {
      const char* srcA[2] = {(const char*)ahp[kt] + (size_t)m0 * 256,
                             (const char*)alp[kt] + (size_t)m0 * 256};
      const char* srcW[2] = {(const char*)wh, (const char*)wl};
      const int wRB = wRowShorts * 2;
      const int ktB = kt * 256;
#pragma unroll
      for (int ci = 0; ci < 16; ++ci) {
        int c = w * 16 + ci;
        int plane = c >> 5;
        int sub = c & 31;
        int r = (sub << 2) + (lane >> 4);
        const char* src;
        if (plane < 2) src = srcA[plane] + (size_t)r * 256 + (lane & 15) * 16;
        else           src = srcW[plane - 2] + (size_t)r * wRB + ktB + (lane & 15) * 16;
        void* dst = (char*)lds + (size_t)plane * 32768 + (size_t)sub * 1024;
        __builtin_amdgcn_global_load_lds(
            (const __attribute__((address_space(1))) u32*)src,
            (__attribute__((address_space(3))) u32*)dst, 16, 0, 0);
      }
    }
    __syncthreads();
#pragma unroll
    for (int kk = 0; kk < 4; ++kk) {
      int k0 = kk * 32 + (lane >> 4) * 8;
      bf8 afh[4], afl[4];
#pragma unroll
      for (int rt = 0; rt < 4; ++rt) {
        int row = wr * 64 + rt * 16 + (lane & 15);
        int kp = k0 ^ ((row & 7) << 3);
        afh[rt] = *(const bf8*)&lds[0][row][kp];
        afl[rt] = *(const bf8*)&lds[1][row][kp];
      }
      bf8 bfh[2], bfl[2];
#pragma unroll
      for (int ct = 0; ct < 2; ++ct) {
        int orow = wc * 32 + ct * 16 + (lane & 15);
        int kp = k0 ^ ((orow & 7) << 3);
        bfh[ct] = *(const bf8*)&lds[2][orow][kp];
        bfl[ct] = *(const bf8*)&lds[3][orow][kp];
      }
#pragma unroll
      for (int rt = 0; rt < 4; ++rt)
#pragma unroll
        for (int ct = 0; ct < 2; ++ct) {
          acc[rt][ct] = mfma16(afh[rt], bfh[ct], acc[rt][ct]);
          acc[rt][ct] = mfma16(afh[rt], bfl[ct], acc[rt][ct]);
          acc[rt][ct] = mfma16(afl[rt], bfh[ct], acc[rt][ct]);
        }
    }
    if (kt + 1 < NT) __syncthreads();
  }

  // epilogue
#pragma unroll
  for (int ct = 0; ct < 2; ++ct) {
    int col = wc * 32 + ct * 16 + (lane & 15);
    int curGrp = -1;
    u32 curKey = 0;
#pragma unroll
    for (int rt = 0; rt < 4; ++rt) {
      int rbase = m0 + wr * 64 + rt * 16 + ((lane >> 4) << 2);
#pragma unroll
      for (int reg = 0; reg < 4; ++reg) {
        int row = rbase + reg;
        float v = acc[rt][ct][reg];
        if (MODE == 0) v += bias[col];
        if (MODE == 1) v += bias[(row / 513) * HD + col];
        if (MODE != 2) v = fmaxf(v, 0.0f);
        if (MODE != 2) {
          unsigned short h = f2bf(v);
          unsigned short l2 = f2bf(v - bf2f(h));
          size_t pos = (size_t)row * HD + (col ^ ((row & 7) << 3));
          oh[pos] = (short)h;
          ol[pos] = (short)l2;
        }
        if (MODE == 0 || MODE == 2) {
          if (row < M) {
            int gg = row / 513;
            u32 key = xf(v);
            if (gg != curGrp) {
              if (curGrp >= 0) atomicMax(&redU[curGrp * HD + col], curKey);
              curGrp = gg; curKey = key;
            } else {
              curKey = max(curKey, key);
            }
          }
        }
      }
    }
    if ((MODE == 0 || MODE == 2) && curGrp >= 0)
      atomicMax(&redU[curGrp * HD + col], curKey);
  }
}

// gvec[g][c] = gb[c] + sum_j tmax[g][j] * gw[c][128+j]
__global__ void gvec_kernel(const u32* __restrict__ tmaxU, const float* __restrict__ gw,
                            const float* __restrict__ gb, float* __restrict__ gvec) {
  int g = blockIdx.x, c = threadIdx.x;
  __shared__ float sm[HD];
  sm[c] = xinv(tmaxU[g * HD + c]);
  __syncthreads();
  const float* wr = gw + (size_t)c * (2 * HD) + HD;
  float s = gb[c];
  for (int j = 0; j < HD; ++j) s += sm[j] * wr[j];
  gvec[g * HD + c] = s;
}

__global__ void batchmax_kernel(const u32* __restrict__ goutU,
                                const float* __restrict__ bout,
                                float* __restrict__ out) {
  int b = blockIdx.x, c = threadIdx.x;
  float m = -3.4e38f;
  for (int k = 0; k < K_FPS; ++k) m = fmaxf(m, xinv(goutU[(size_t)(b * K_FPS + k) * HD + c]));
  out[b * HD + c] = m + bout[c];
}

// ---------------------------------------------------------------------------
// Centroid MLP path (unchanged from round 1 - verified).
// ---------------------------------------------------------------------------
__device__ __forceinline__ void block_ln(float* h, int n, const float* __restrict__ gam,
                                         const float* __restrict__ bet, float* red,
                                         int tid, bool relu) {
  float v = (tid < n) ? h[tid] : 0.0f;
  red[tid] = v;
  __syncthreads();
  for (int s = 128; s > 0; s >>= 1) { if (tid < s) red[tid] += red[tid + s]; __syncthreads(); }
  float mean = red[0] / n;
  __syncthreads();
  float d = (tid < n) ? (h[tid] - mean) : 0.0f;
  red[tid] = d * d;
  __syncthreads();
  for (int s = 128; s > 0; s >>= 1) { if (tid < s) red[tid] += red[tid + s]; __syncthreads(); }
  float var = red[0] / n;
  __syncthreads();
  if (tid < n) {
    float o = (h[tid] - mean) / sqrtf(var + 1e-5f) * gam[tid] + bet[tid];
    if (relu) o = fmaxf(o, 0.0f);
    h[tid] = o;
  }
  __syncthreads();
}

__global__ __launch_bounds__(256) void cpath_kernel(const float* __restrict__ cxyz,
    const float* __restrict__ w0, const float* __restrict__ b0,
    const float* __restrict__ g0, const float* __restrict__ e0,
    const float* __restrict__ w1, const float* __restrict__ b1,
    const float* __restrict__ g1, const float* __restrict__ e1,
    const float* __restrict__ w2, const float* __restrict__ b2,
    const float* __restrict__ g2, const float* __restrict__ e2,
    const float* __restrict__ fw, const float* __restrict__ fb,
    const float* __restrict__ fg, const float* __restrict__ fe,
    float* __restrict__ out) {
  int b = blockIdx.x, tid = threadIdx.x;
  __shared__ float h[256];
  __shared__ float hb[256];
  __shared__ float cmax[256];
  __shared__ float red[256];
  cmax[tid] = -1e30f;
  __syncthreads();
  for (int k = 0; k < K_FPS; ++k) {
    const float* cp = cxyz + (size_t)(b * K_FPS + k) * 3;
    float p0 = cp[0], p1 = cp[1], p2 = cp[2];
    if (tid < 64)
      h[tid] = b0[tid] + p0 * w0[tid * 3 + 0] + p1 * w0[tid * 3 + 1] + p2 * w0[tid * 3 + 2];
    __syncthreads();
    block_ln(h, 64, g0, e0, red, tid, true);
    if (tid < 128) {
      float s = b1[tid];
      const float* wr = w1 + (size_t)tid * 64;
      for (int j = 0; j < 64; ++j) s += h[j] * wr[j];
      hb[tid] = s;
    }
    __syncthreads();
    block_ln(hb, 128, g1, e1, red, tid, true);
    {
      float s = b2[tid];
      const float* wr = w2 + (size_t)tid * 128;
      for (int j = 0; j < 128; ++j) s += hb[j] * wr[j];
      __syncthreads();
      h[tid] = s;
    }
    __syncthreads();
    block_ln(h, 256, g2, e2, red, tid, true);
    cmax[tid] = fmaxf(cmax[tid], h[tid]);
    __syncthreads();
  }
  if (tid < 128) {
    float s = fb[tid];
    const float* wr = fw + (size_t)tid * 256;
    for (int j = 0; j < 256; ++j) s += cmax[j] * wr[j];
    h[tid] = s;
  }
  __syncthreads();
  block_ln(h, 128, fg, fe, red, tid, false);
  if (tid < 128) out[b * HD + tid] = h[tid];
}

// ---------------------------------------------------------------------------
extern "C" void kernel_launch(void* const* d_in, const int* in_sizes, int n_in,
                              void* d_out, int out_size, void* d_ws, size_t ws_size,
                              hipStream_t stream) {
  (void)in_sizes; (void)n_in; (void)out_size;
  const float* x          = (const float*)d_in[0];
  const float* conv_in_w  = (const float*)d_in[1];
  const float* conv_in_b  = (const float*)d_in[2];
  const float* layer_w    = (const float*)d_in[3];
  const float* layer_b    = (const float*)d_in[4];
  const float* glayer_w   = (const float*)d_in[5];
  const float* glayer_b   = (const float*)d_in[6];
  const float* conv_out_w = (const float*)d_in[7];
  const float* conv_out_b = (const float*)d_in[8];
  const float* mlp_w0 = (const float*)d_in[9];
  const float* mlp_b0 = (const float*)d_in[10];
  const float* ln0_g  = (const float*)d_in[11];
  const float* ln0_b  = (const float*)d_in[12];
  const float* mlp_w1 = (const float*)d_in[13];
  const float* mlp_b1 = (const float*)d_in[14];
  const float* ln1_g  = (const float*)d_in[15];
  const float* ln1_b  = (const float*)d_in[16];
  const float* mlp_w2 = (const float*)d_in[17];
  const float* mlp_b2 = (const float*)d_in[18];
  const float* ln2_g  = (const float*)d_in[19];
  const float* ln2_b  = (const float*)d_in[20];
  const float* fp_w   = (const float*)d_in[21];
  const float* fp_b   = (const float*)d_in[22];
  const float* fp_ln_g = (const float*)d_in[23];
  const float* fp_ln_b = (const float*)d_in[24];

  char* ws = (char*)d_ws;
  size_t off = 0;
  auto carve = [&](size_t bytes) -> void* {
    void* p = ws + off;
    off += (bytes + 255) & ~(size_t)255;
    return p;
  };
  int* cents   = (int*)carve(256 * 4);
  float* cxyz  = (float*)carve(256 * 3 * 4);
  float* grouped = (float*)carve((size_t)256 * NP * 3 * 4);
  u32* goutU   = (u32*)carve(256 * HD * 4);
  u32* tmaxU   = (u32*)carve(257 * HD * 4);
  float* gvec  = (float*)carve(257 * HD * 4);
  short* w1h = (short*)carve(4 * 16384 * 2);
  short* w1l = (short*)carve(4 * 16384 * 2);
  short* w2h = (short*)carve(4 * 16384 * 2);
  short* w2l = (short*)carve(4 * 16384 * 2);
  short* coh = (short*)carve(65536 * 2);
  short* col_ = (short*)carve(65536 * 2);
  size_t fixed = off;

  int C = 8;
  const int cands[6] = {256, 128, 64, 32, 16, 8};
  for (int ci = 0; ci < 6; ++ci) {
    int Cc = cands[ci];
    size_t Mp = ((size_t)(513 * Cc + 127) / 128) * 128;
    size_t need = fixed + 12 * ((Mp * HD * 2 + 255) & ~(size_t)255) + 65536;
    if (need <= ws_size) { C = Cc; break; }
  }
  int Mp = (int)(((size_t)(513 * C + 127) / 128) * 128);
  size_t planeB = (size_t)Mp * HD * 2;
  short* y0h = (short*)carve(planeB); short* y0l = (short*)carve(planeB);
  short* th  = (short*)carve(planeB); short* tl  = (short*)carve(planeB);
  short* fh[4]; short* fl[4];
  for (int l = 0; l < 4; ++l) { fh[l] = (short*)carve(planeB); fl[l] = (short*)carve(planeB); }

  fps_kernel<<<B_SZ, 1024, 0, stream>>>(x, cents);
  ballq_kernel<<<256, 1024, 0, stream>>>(x, cents, cxyz, grouped);
  wprep_kernel<<<768, 256, 0, stream>>>(layer_w, glayer_w, conv_out_w,
                                        w1h, w1l, w2h, w2l, coh, col_);
  initu_kernel<<<(256 * HD + 255) / 256, 256, 0, stream>>>(goutU, 256 * HD, 0x00800000u);

  int M = C * 513;
  int nb = Mp / 128;
  for (int g0 = 0; g0 < 256; g0 += C) {
    conv_in_kernel<<<(Mp * HD + 255) / 256, 256, 0, stream>>>(
        grouped + (size_t)g0 * NP * 3, conv_in_w, conv_in_b, y0h, y0l, M, Mp);
    const short* inH = y0h; const short* inL = y0l;
    for (int l = 0; l < 4; ++l) {
      initu_kernel<<<(C * HD + 255) / 256, 256, 0, stream>>>(tmaxU, C * HD, 0u);
      mfgemm<0><<<nb, 512, 0, stream>>>(
          inH, inL, inH, inL, inH, inL, inH, inL,
          w1h + (size_t)l * 16384, w1l + (size_t)l * 16384, 128,
          layer_b + l * HD, th, tl, tmaxU, M);
      gvec_kernel<<<C, HD, 0, stream>>>(tmaxU, glayer_w + (size_t)l * HD * 2 * HD,
                                        glayer_b + l * HD, gvec);
      mfgemm<1><<<nb, 512, 0, stream>>>(
          th, tl, th, tl, th, tl, th, tl,
          w2h + (size_t)l * 16384, w2l + (size_t)l * 16384, 128,
          gvec, fh[l], fl[l], nullptr, M);
      inH = fh[l]; inL = fl[l];
    }
    mfgemm<2><<<nb, 512, 0, stream>>>(
        fh[0], fl[0], fh[1], fl[1], fh[2], fl[2], fh[3], fl[3],
        coh, col_, 512, nullptr, nullptr, nullptr, goutU + (size_t)g0 * HD, M);
  }
  batchmax_kernel<<<B_SZ, HD, 0, stream>>>(goutU, conv_out_b, (float*)d_out);
  cpath_kernel<<<B_SZ, 256, 0, stream>>>(cxyz,
      mlp_w0, mlp_b0, ln0_g, ln0_b,
      mlp_w1, mlp_b1, ln1_g, ln1_b,
      mlp_w2, mlp_b2, ln2_g, ln2_b,
      fp_w, fp_b, fp_ln_g, fp_ln_b,
      (float*)d_out + B_SZ * HD);
}

// Round 4
// 1042.515 us; speedup vs baseline: 2.1333x; 1.0998x over previous
//
#include <hip/hip_runtime.h>
#include <cstdint>
#include <cstddef>

#define N_PTS 65536
#define B_SZ 32
#define K_FPS 8
#define GRP 512
#define NP 513
#define HD 128
#define R2C 0.04f
#define BIGF 1e10f

typedef unsigned int u32;
typedef unsigned long long u64;
using bf8  = __attribute__((ext_vector_type(8))) short;   // 8 x bf16 bits
using f32x4 = __attribute__((ext_vector_type(4))) float;

// ---- helpers ---------------------------------------------------------------
__device__ __forceinline__ unsigned short f2bf(float f) {
  u32 u = __float_as_uint(f);
  u32 r = (u + 0x7FFFu + ((u >> 16) & 1u)) >> 16;   // RNE
  return (unsigned short)r;
}
__device__ __forceinline__ float bf2f(unsigned short h) {
  return __uint_as_float(((u32)h) << 16);
}
// monotone float<->uint for atomicMax
__device__ __forceinline__ u32 xf(float v) {
  u32 u = __float_as_uint(v);
  return (u & 0x80000000u) ? ~u : (u | 0x80000000u);
}
__device__ __forceinline__ float xinv(u32 u) {
  return (u & 0x80000000u) ? __uint_as_float(u & 0x7FFFFFFFu) : __uint_as_float(~u);
}
__device__ __forceinline__ f32x4 mfma16(bf8 a, bf8 b, f32x4 c) {
  return __builtin_amdgcn_mfma_f32_16x16x32_bf16(a, b, c, 0, 0, 0);
}

// ---------------------------------------------------------------------------
// FPS step IT: 2048 blocks (32 batches x 64 slices of 1024 pts), 256 threads.
// dist in global fp32; per-batch winner via packed u64 atomicMax
// key = xf(d)<<32 | (0xFFFFFFFF - idx)  -> max == (max d, min idx on tie).
// ---------------------------------------------------------------------------
template <int IT>
__global__ __launch_bounds__(256) void fps_step(const float* __restrict__ x,
                                                float* __restrict__ dist,
                                                u64* __restrict__ slots,
                                                int* __restrict__ cents) {
  int blk = blockIdx.x;
  int b = blk >> 6, s = blk & 63;
  int tid = threadIdx.x;
  const float* xb = x + (size_t)b * N_PTS * 3;
  float* db = dist + (size_t)b * N_PTS;
  __shared__ float sc[3];
  __shared__ int sidx;
  if (tid == 0) {
    int ci = 0;
    if (IT > 0) ci = (int)(0xFFFFFFFFu - (u32)(slots[(IT - 1) * B_SZ + b]));
    sidx = ci;
    sc[0] = xb[ci * 3 + 0]; sc[1] = xb[ci * 3 + 1]; sc[2] = xb[ci * 3 + 2];
  }
  __syncthreads();
  if (s == 0 && tid == 0) cents[b * K_FPS + IT] = sidx;
  float c0 = sc[0], c1 = sc[1], c2 = sc[2];
  float best = -1.0f; int bi = 0;
  int base = s * 1024;
#pragma unroll
  for (int j = 0; j < 4; ++j) {
    int i = base + j * 256 + tid;
    float dx = xb[i * 3 + 0] - c0;
    float dy = xb[i * 3 + 1] - c1;
    float dz = xb[i * 3 + 2] - c2;
    float d = dx * dx + dy * dy + dz * dz;
    float nd = (IT == 0) ? d : fminf(db[i], d);
    db[i] = nd;
    if (nd > best) { best = nd; bi = i; }
  }
  for (int off = 32; off > 0; off >>= 1) {
    float ov = __shfl_down(best, off);
    int oi = __shfl_down(bi, off);
    if (ov > best || (ov == best && oi < bi)) { best = ov; bi = oi; }
  }
  __shared__ float wv[4]; __shared__ int wi[4];
  if ((tid & 63) == 0) { wv[tid >> 6] = best; wi[tid >> 6] = bi; }
  __syncthreads();
  if (tid == 0) {
    float bv = wv[0]; int bx = wi[0];
    for (int k = 1; k < 4; ++k)
      if (wv[k] > bv || (wv[k] == bv && wi[k] < bx)) { bv = wv[k]; bx = wi[k]; }
    if (IT < K_FPS - 1) {
      u64 key = ((u64)xf(bv) << 32) | (u64)(0xFFFFFFFFu - (u32)bx);
      atomicMax(&slots[IT * B_SZ + b], key);
    }
  }
}

// ---------------------------------------------------------------------------
// Ball query: 1024 threads, contiguous 64-pt range per thread, bitmask + scan.
// ---------------------------------------------------------------------------
__global__ __launch_bounds__(1024) void ballq_kernel(const float* __restrict__ x,
                                                     const int* __restrict__ cents,
                                                     float* __restrict__ cxyz,
                                                     float* __restrict__ grouped) {
  int g = blockIdx.x, b = g >> 3, tid = threadIdx.x;
  const float* xb = x + (size_t)b * N_PTS * 3;
  __shared__ int sPref[1024];
  __shared__ int s_in[GRP];
  __shared__ int s_out[GRP];
  __shared__ float sc[3];
  if (tid == 0) {
    int ci = cents[g];
    sc[0] = xb[ci * 3 + 0]; sc[1] = xb[ci * 3 + 1]; sc[2] = xb[ci * 3 + 2];
  }
  __syncthreads();
  float c0 = sc[0], c1 = sc[1], c2 = sc[2];
  int base = tid * 64;
  unsigned long long bm = 0ull;
  int cnt = 0;
  for (int j = 0; j < 64; ++j) {
    int i = base + j;
    float dx = xb[i * 3 + 0] - c0;
    float dy = xb[i * 3 + 1] - c1;
    float dz = xb[i * 3 + 2] - c2;
    float d = dx * dx + dy * dy + dz * dz;
    bool inr = !(d > R2C);
    if (inr) { bm |= (1ull << j); ++cnt; }
  }
  sPref[tid] = cnt;
  __syncthreads();
  for (int off = 1; off < 1024; off <<= 1) {
    int add = (tid >= off) ? sPref[tid - off] : 0;
    __syncthreads();
    sPref[tid] += add;
    __syncthreads();
  }
  int inc = sPref[tid];
  int exc = inc - cnt;
  int outExc = base - exc;
  {
    int ii = exc, oo = outExc;
    for (int j = 0; j < 64; ++j) {
      if ((bm >> j) & 1ull) { if (ii < GRP) s_in[ii] = base + j; ++ii; }
      else                  { if (oo < GRP) s_out[oo] = base + j; ++oo; }
    }
  }
  __syncthreads();
  int incnt = min(sPref[1023], GRP);
  if (tid == 0) {
    cxyz[g * 3 + 0] = c0; cxyz[g * 3 + 1] = c1; cxyz[g * 3 + 2] = c2;
    float* o0 = grouped + (size_t)g * NP * 3;
    o0[0] = c0; o0[1] = c1; o0[2] = c2;
  } else if (tid <= GRP) {
    int j = tid - 1;
    int src = (j < incnt) ? s_in[j] : s_out[j - incnt];
    float* o = grouped + ((size_t)g * NP + 1 + j) * 3;
    o[0] = xb[src * 3 + 0] - c0;
    o[1] = xb[src * 3 + 1] - c1;
    o[2] = xb[src * 3 + 2] - c2;
  }
}

// ---------------------------------------------------------------------------
// Weight prep: fp32 -> swizzled bf16 hi/lo planes.  plane[o][k ^ ((o&7)<<3)]
// ---------------------------------------------------------------------------
__global__ void wprep_kernel(const float* __restrict__ layer_w,
                             const float* __restrict__ glayer_w,
                             const float* __restrict__ conv_out_w,
                             short* __restrict__ w1h, short* __restrict__ w1l,
                             short* __restrict__ w2h, short* __restrict__ w2l,
                             short* __restrict__ coh, short* __restrict__ col_) {
  int id = blockIdx.x * blockDim.x + threadIdx.x;
  float v; short *dh, *dl; size_t dpos;
  if (id < 65536) {
    int l = id >> 14, o = (id >> 7) & 127, k = id & 127;
    v = layer_w[(size_t)l * 16384 + o * 128 + k];
    dpos = (size_t)l * 16384 + o * 128 + (k ^ ((o & 7) << 3));
    dh = w1h; dl = w1l;
  } else if (id < 131072) {
    int t = id - 65536;
    int l = t >> 14, o = (t >> 7) & 127, k = t & 127;
    v = glayer_w[(size_t)l * 32768 + o * 256 + k];
    dpos = (size_t)l * 16384 + o * 128 + (k ^ ((o & 7) << 3));
    dh = w2h; dl = w2l;
  } else if (id < 196608) {
    int t = id - 131072;
    int o = t >> 9, k = t & 511;
    v = conv_out_w[(size_t)o * 512 + k];
    dpos = (size_t)o * 512 + (k ^ ((o & 7) << 3));
    dh = coh; dl = col_;
  } else return;
  unsigned short h = f2bf(v);
  dh[dpos] = (short)h;
  dl[dpos] = (short)f2bf(v - bf2f(h));
}

// ---------------------------------------------------------------------------
// conv_in -> y0 planes (swizzled hi/lo), pad rows zeroed.
// ---------------------------------------------------------------------------
__global__ void conv_in_kernel(const float* __restrict__ gp,
                               const float* __restrict__ W,
                               const float* __restrict__ bias,
                               short* __restrict__ oh, short* __restrict__ ol,
                               int M, int Mp) {
  int idx = blockIdx.x * blockDim.x + threadIdx.x;
  if (idx >= Mp * HD) return;
  int r = idx >> 7, c = idx & 127;
  float v = 0.0f;
  if (r < M) {
    const float* p = gp + (size_t)r * 3;
    v = bias[c] + p[0] * W[c * 3 + 0] + p[1] * W[c * 3 + 1] + p[2] * W[c * 3 + 2];
    v = fmaxf(v, 0.0f);
  }
  unsigned short h = f2bf(v);
  size_t pos = (size_t)r * HD + (c ^ ((r & 7) << 3));
  oh[pos] = (short)h;
  ol[pos] = (short)f2bf(v - bf2f(h));
}

__global__ void initu_kernel(u32* p, int n, u32 v) {
  int i = blockIdx.x * blockDim.x + threadIdx.x;
  if (i < n) p[i] = v;
}

// ---------------------------------------------------------------------------
// bf16x3-split MFMA GEMM.  out[M][128] = f(A[M][128] @ W^T)
// 256 threads / 4 waves, tile 128x128, wave-tile 64x64, BK=64, LDS 64 KiB
// -> 2 blocks/CU for stage/compute overlap.
// MODE 0: +bias[col], relu, write planes, atomicMax tmaxU[grp][col]
// MODE 1: +gvec[grp][col], relu, write planes
// MODE 2: K=512 over 4 feat buffers, no bias/relu, atomicMax redU[grp][col]
// ---------------------------------------------------------------------------
template <int MODE>
__global__ __launch_bounds__(256, 2) void mfgemm(
    const short* __restrict__ a0h, const short* __restrict__ a0l,
    const short* __restrict__ a1h, const short* __restrict__ a1l,
    const short* __restrict__ a2h, const short* __restrict__ a2l,
    const short* __restrict__ a3h, const short* __restrict__ a3l,
    const short* __restrict__ wh, const short* __restrict__ wl,
    int wRowShorts,
    const float* __restrict__ bias,
    short* __restrict__ oh, short* __restrict__ ol,
    u32* __restrict__ redU,
    int M) {
  __shared__ short lds[4][128][64];       // Ah, Al, Wh, Wl (64 KiB)
  const int tid = threadIdx.x;
  const int lane = tid & 63, w = tid >> 6;
  const int wr = w >> 1, wc = w & 1;      // 2x2 wave grid, 64x64 wave-tile
  const int m0 = blockIdx.x * 128;
  const int wRB = wRowShorts * 2;

  f32x4 acc[4][4];
#pragma unroll
  for (int i = 0; i < 4; ++i)
#pragma unroll
    for (int j = 0; j < 4; ++j) acc[i][j] = (f32x4){0.f, 0.f, 0.f, 0.f};

  const int NH = (MODE == 2) ? 8 : 2;     // K-halves of 64
  const short* ahp[4] = {a0h, a1h, a2h, a3h};
  const short* alp[4] = {a0l, a1l, a2l, a3l};

#pragma unroll
  for (int hf = 0; hf < NH; ++hf) {
    {
      const char* pAh = (const char*)ahp[hf >> 1] + (size_t)m0 * 256 + (hf & 1) * 128;
      const char* pAl = (const char*)alp[hf >> 1] + (size_t)m0 * 256 + (hf & 1) * 128;
      const char* pWh = (const char*)wh + hf * 128;
      const char* pWl = (const char*)wl + hf * 128;
#pragma unroll
      for (int i = 0; i < 16; ++i) {
        int c2 = i * 256 + tid;           // chunk id 0..4095
        int plane = c2 >> 10;
        int idx = c2 & 1023;
        int row = idx >> 3, ch = idx & 7;
        const char* s = (plane == 0) ? pAh : (plane == 1) ? pAl
                       : (plane == 2) ? pWh : pWl;
        int rb = (plane < 2) ? 256 : wRB;
        const char* src = s + (size_t)row * rb + ch * 16;
        void* dst = (char*)lds + (size_t)c2 * 16;
        __builtin_amdgcn_global_load_lds(
            (const __attribute__((address_space(1))) u32*)src,
            (__attribute__((address_space(3))) u32*)dst, 16, 0, 0);
      }
    }
    __syncthreads();
#pragma unroll
    for (int kk = 0; kk < 2; ++kk) {
      int k0 = kk * 32 + (lane >> 4) * 8;
      bf8 afh[4], afl[4], bfh[4], bfl[4];
#pragma unroll
      for (int rt = 0; rt < 4; ++rt) {
        int row = wr * 64 + rt * 16 + (lane & 15);
        int kp = k0 ^ ((row & 7) << 3);
        afh[rt] = *(const bf8*)&lds[0][row][kp];
        afl[rt] = *(const bf8*)&lds[1][row][kp];
      }
#pragma unroll
      for (int ct = 0; ct < 4; ++ct) {
        int orow = wc * 64 + ct * 16 + (lane & 15);
        int kp = k0 ^ ((orow & 7) << 3);
        bfh[ct] = *(const bf8*)&lds[2][orow][kp];
        bfl[ct] = *(const bf8*)&lds[3][orow][kp];
      }
#pragma unroll
      for (int rt = 0; rt < 4; ++rt)
#pragma unroll
        for (int ct = 0; ct < 4; ++ct) {
          acc[rt][ct] = mfma16(afh[rt], bfh[ct], acc[rt][ct]);
          acc[rt][ct] = mfma16(afh[rt], bfl[ct], acc[rt][ct]);
          acc[rt][ct] = mfma16(afl[rt], bfh[ct], acc[rt][ct]);
        }
    }
    if (hf + 1 < NH) __syncthreads();
  }

  // epilogue
#pragma unroll
  for (int ct = 0; ct < 4; ++ct) {
    int col = wc * 64 + ct * 16 + (lane & 15);
    int curGrp = -1;
    u32 curKey = 0;
#pragma unroll
    for (int rt = 0; rt < 4; ++rt) {
      int rbase = m0 + wr * 64 + rt * 16 + ((lane >> 4) << 2);
#pragma unroll
      for (int reg = 0; reg < 4; ++reg) {
        int row = rbase + reg;
        float v = acc[rt][ct][reg];
        if (MODE == 0) v += bias[col];
        if (MODE == 1) v += bias[(row / 513) * HD + col];
        if (MODE != 2) {
          v = fmaxf(v, 0.0f);
          unsigned short h = f2bf(v);
          unsigned short l2 = f2bf(v - bf2f(h));
          size_t pos = (size_t)row * HD + (col ^ ((row & 7) << 3));
          oh[pos] = (short)h;
          ol[pos] = (short)l2;
        }
        if (MODE == 0 || MODE == 2) {
          if (row < M) {
            int gg = row / 513;
            u32 key = xf(v);
            if (gg != curGrp) {
              if (curGrp >= 0) atomicMax(&redU[curGrp * HD + col], curKey);
              curGrp = gg; curKey = key;
            } else {
              curKey = max(curKey, key);
            }
          }
        }
      }
    }
    if ((MODE == 0 || MODE == 2) && curGrp >= 0)
      atomicMax(&redU[curGrp * HD + col], curKey);
  }
}

// gvec[g][c] = gb[c] + sum_j tmax[g][j] * gw[c][128+j]
__global__ void gvec_kernel(const u32* __restrict__ tmaxU, const float* __restrict__ gw,
                            const float* __restrict__ gb, float* __restrict__ gvec) {
  int g = blockIdx.x, c = threadIdx.x;
  __shared__ float sm[HD];
  sm[c] = xinv(tmaxU[g * HD + c]);
  __syncthreads();
  const float* wr = gw + (size_t)c * (2 * HD) + HD;
  float s = gb[c];
  for (int j = 0; j < HD; ++j) s += sm[j] * wr[j];
  gvec[g * HD + c] = s;
}

__global__ void batchmax_kernel(const u32* __restrict__ goutU,
                                const float* __restrict__ bout,
                                float* __restrict__ out) {
  int b = blockIdx.x, c = threadIdx.x;
  float m = -3.4e38f;
  for (int k = 0; k < K_FPS; ++k) m = fmaxf(m, xinv(goutU[(size_t)(b * K_FPS + k) * HD + c]));
  out[b * HD + c] = m + bout[c];
}

// ---------------------------------------------------------------------------
// Centroid MLP path: cpathA = one block per (b,k) centroid, atomicMax into
// cmaxU; cpathB = final matvec + LN per batch.
// ---------------------------------------------------------------------------
__device__ __forceinline__ void block_ln(float* h, int n, const float* __restrict__ gam,
                                         const float* __restrict__ bet, float* red,
                                         int tid, bool relu) {
  float v = (tid < n) ? h[tid] : 0.0f;
  red[tid] = v;
  __syncthreads();
  for (int s = 128; s > 0; s >>= 1) { if (tid < s) red[tid] += red[tid + s]; __syncthreads(); }
  float mean = red[0] / n;
  __syncthreads();
  float d = (tid < n) ? (h[tid] - mean) : 0.0f;
  red[tid] = d * d;
  __syncthreads();
  for (int s = 128; s > 0; s >>= 1) { if (tid < s) red[tid] += red[tid + s]; __syncthreads(); }
  float var = red[0] / n;
  __syncthreads();
  if (tid < n) {
    float o = (h[tid] - mean) / sqrtf(var + 1e-5f) * gam[tid] + bet[tid];
    if (relu) o = fmaxf(o, 0.0f);
    h[tid] = o;
  }
  __syncthreads();
}

__global__ __launch_bounds__(256) void cpathA_kernel(const float* __restrict__ cxyz,
    const float* __restrict__ w0, const float* __restrict__ b0,
    const float* __restrict__ g0, const float* __restrict__ e0,
    const float* __restrict__ w1, const float* __restrict__ b1,
    const float* __restrict__ g1, const float* __restrict__ e1,
    const float* __restrict__ w2, const float* __restrict__ b2,
    const float* __restrict__ g2, const float* __restrict__ e2,
    u32* __restrict__ cmaxU) {
  int g = blockIdx.x, b = g >> 3, tid = threadIdx.x;
  __shared__ float h[256];
  __shared__ float hb[256];
  __shared__ float red[256];
  const float* cp = cxyz + (size_t)g * 3;
  float p0 = cp[0], p1 = cp[1], p2 = cp[2];
  if (tid < 64)
    h[tid] = b0[tid] + p0 * w0[tid * 3 + 0] + p1 * w0[tid * 3 + 1] + p2 * w0[tid * 3 + 2];
  __syncthreads();
  block_ln(h, 64, g0, e0, red, tid, true);
  if (tid < 128) {
    float s = b1[tid];
    const float* wr = w1 + (size_t)tid * 64;
    for (int j = 0; j < 64; ++j) s += h[j] * wr[j];
    hb[tid] = s;
  }
  __syncthreads();
  block_ln(hb, 128, g1, e1, red, tid, true);
  {
    float s = b2[tid];
    const float* wr = w2 + (size_t)tid * 128;
    for (int j = 0; j < 128; ++j) s += hb[j] * wr[j];
    __syncthreads();
    h[tid] = s;
  }
  __syncthreads();
  block_ln(h, 256, g2, e2, red, tid, true);
  atomicMax(&cmaxU[b * 256 + tid], xf(h[tid]));
}

__global__ __launch_bounds__(256) void cpathB_kernel(const u32* __restrict__ cmaxU,
    const float* __restrict__ fw, const float* __restrict__ fb,
    const float* __restrict__ fg, const float* __restrict__ fe,
    float* __restrict__ out) {
  int b = blockIdx.x, tid = threadIdx.x;
  __shared__ float cm[256];
  __shared__ float h[256];
  __shared__ float red[256];
  cm[tid] = xinv(cmaxU[b * 256 + tid]);
  __syncthreads();
  if (tid < 128) {
    float s = fb[tid];
    const float* wr = fw + (size_t)tid * 256;
    for (int j = 0; j < 256; ++j) s += cm[j] * wr[j];
    h[tid] = s;
  }
  __syncthreads();
  block_ln(h, 128, fg, fe, red, tid, false);
  if (tid < 128) out[b * HD + tid] = h[tid];
}

// ---------------------------------------------------------------------------
extern "C" void kernel_launch(void* const* d_in, const int* in_sizes, int n_in,
                              void* d_out, int out_size, void* d_ws, size_t ws_size,
                              hipStream_t stream) {
  (void)in_sizes; (void)n_in; (void)out_size;
  const float* x          = (const float*)d_in[0];
  const float* conv_in_w  = (const float*)d_in[1];
  const float* conv_in_b  = (const float*)d_in[2];
  const float* layer_w    = (const float*)d_in[3];
  const float* layer_b    = (const float*)d_in[4];
  const float* glayer_w   = (const float*)d_in[5];
  const float* glayer_b   = (const float*)d_in[6];
  const float* conv_out_w = (const float*)d_in[7];
  const float* conv_out_b = (const float*)d_in[8];
  const float* mlp_w0 = (const float*)d_in[9];
  const float* mlp_b0 = (const float*)d_in[10];
  const float* ln0_g  = (const float*)d_in[11];
  const float* ln0_b  = (const float*)d_in[12];
  const float* mlp_w1 = (const float*)d_in[13];
  const float* mlp_b1 = (const float*)d_in[14];
  const float* ln1_g  = (const float*)d_in[15];
  const float* ln1_b  = (const float*)d_in[16];
  const float* mlp_w2 = (const float*)d_in[17];
  const float* mlp_b2 = (const float*)d_in[18];
  const float* ln2_g  = (const float*)d_in[19];
  const float* ln2_b  = (const float*)d_in[20];
  const float* fp_w   = (const float*)d_in[21];
  const float* fp_b   = (const float*)d_in[22];
  const float* fp_ln_g = (const float*)d_in[23];
  const float* fp_ln_b = (const float*)d_in[24];

  char* ws = (char*)d_ws;
  size_t off = 0;
  auto carve = [&](size_t bytes) -> void* {
    void* p = ws + off;
    off += (bytes + 255) & ~(size_t)255;
    return p;
  };
  float* fps_dist = (float*)carve((size_t)B_SZ * N_PTS * 4);
  u64* slots   = (u64*)carve(K_FPS * B_SZ * 8);
  int* cents   = (int*)carve(256 * 4);
  float* cxyz  = (float*)carve(256 * 3 * 4);
  float* grouped = (float*)carve((size_t)256 * NP * 3 * 4);
  u32* goutU   = (u32*)carve(256 * HD * 4);
  u32* tmaxU   = (u32*)carve(257 * HD * 4);
  float* gvec  = (float*)carve(257 * HD * 4);
  u32* cmaxU   = (u32*)carve(B_SZ * 256 * 4);
  short* w1h = (short*)carve(4 * 16384 * 2);
  short* w1l = (short*)carve(4 * 16384 * 2);
  short* w2h = (short*)carve(4 * 16384 * 2);
  short* w2l = (short*)carve(4 * 16384 * 2);
  short* coh = (short*)carve(65536 * 2);
  short* col_ = (short*)carve(65536 * 2);
  size_t fixed = off;

  int C = 8;
  const int cands[4] = {64, 32, 16, 8};   // prefer 64: activations L3-resident
  for (int ci = 0; ci < 4; ++ci) {
    int Cc = cands[ci];
    size_t Mp = ((size_t)(513 * Cc + 127) / 128) * 128;
    size_t need = fixed + 12 * ((Mp * HD * 2 + 255) & ~(size_t)255) + 65536;
    if (need <= ws_size) { C = Cc; break; }
  }
  int Mp = (int)(((size_t)(513 * C + 127) / 128) * 128);
  size_t planeB = (size_t)Mp * HD * 2;
  short* y0h = (short*)carve(planeB); short* y0l = (short*)carve(planeB);
  short* th  = (short*)carve(planeB); short* tl  = (short*)carve(planeB);
  short* fh[4]; short* fl[4];
  for (int l = 0; l < 4; ++l) { fh[l] = (short*)carve(planeB); fl[l] = (short*)carve(planeB); }

  // inits (ws is re-poisoned to 0xAA before every launch)
  initu_kernel<<<(K_FPS * B_SZ * 2 + 255) / 256, 256, 0, stream>>>((u32*)slots, K_FPS * B_SZ * 2, 0u);
  initu_kernel<<<(256 * HD + 255) / 256, 256, 0, stream>>>(goutU, 256 * HD, 0x00800000u);
  initu_kernel<<<(B_SZ * 256 + 255) / 256, 256, 0, stream>>>(cmaxU, B_SZ * 256, 0u);

  fps_step<0><<<2048, 256, 0, stream>>>(x, fps_dist, slots, cents);
  fps_step<1><<<2048, 256, 0, stream>>>(x, fps_dist, slots, cents);
  fps_step<2><<<2048, 256, 0, stream>>>(x, fps_dist, slots, cents);
  fps_step<3><<<2048, 256, 0, stream>>>(x, fps_dist, slots, cents);
  fps_step<4><<<2048, 256, 0, stream>>>(x, fps_dist, slots, cents);
  fps_step<5><<<2048, 256, 0, stream>>>(x, fps_dist, slots, cents);
  fps_step<6><<<2048, 256, 0, stream>>>(x, fps_dist, slots, cents);
  fps_step<7><<<2048, 256, 0, stream>>>(x, fps_dist, slots, cents);

  ballq_kernel<<<256, 1024, 0, stream>>>(x, cents, cxyz, grouped);
  wprep_kernel<<<768, 256, 0, stream>>>(layer_w, glayer_w, conv_out_w,
                                        w1h, w1l, w2h, w2l, coh, col_);

  int M = C * 513;
  int nb = Mp / 128;
  for (int g0 = 0; g0 < 256; g0 += C) {
    conv_in_kernel<<<(Mp * HD + 255) / 256, 256, 0, stream>>>(
        grouped + (size_t)g0 * NP * 3, conv_in_w, conv_in_b, y0h, y0l, M, Mp);
    const short* inH = y0h; const short* inL = y0l;
    for (int l = 0; l < 4; ++l) {
      initu_kernel<<<(C * HD + 255) / 256, 256, 0, stream>>>(tmaxU, C * HD, 0u);
      mfgemm<0><<<nb, 256, 0, stream>>>(
          inH, inL, inH, inL, inH, inL, inH, inL,
          w1h + (size_t)l * 16384, w1l + (size_t)l * 16384, 128,
          layer_b + l * HD, th, tl, tmaxU, M);
      gvec_kernel<<<C, HD, 0, stream>>>(tmaxU, glayer_w + (size_t)l * HD * 2 * HD,
                                        glayer_b + l * HD, gvec);
      mfgemm<1><<<nb, 256, 0, stream>>>(
          th, tl, th, tl, th, tl, th, tl,
          w2h + (size_t)l * 16384, w2l + (size_t)l * 16384, 128,
          gvec, fh[l], fl[l], nullptr, M);
      inH = fh[l]; inL = fl[l];
    }
    mfgemm<2><<<nb, 256, 0, stream>>>(
        fh[0], fl[0], fh[1], fl[1], fh[2], fl[2], fh[3], fl[3],
        coh, col_, 512, nullptr, nullptr, nullptr, goutU + (size_t)g0 * HD, M);
  }
  batchmax_kernel<<<B_SZ, HD, 0, stream>>>(goutU, conv_out_b, (float*)d_out);
  cpathA_kernel<<<256, 256, 0, stream>>>(cxyz,
      mlp_w0, mlp_b0, ln0_g, ln0_b,
      mlp_w1, mlp_b1, ln1_g, ln1_b,
      mlp_w2, mlp_b2, ln2_g, ln2_b, cmaxU);
  cpathB_kernel<<<B_SZ, 256, 0, stream>>>(cmaxU, fp_w, fp_b, fp_ln_g, fp_ln_b,
                                          (float*)d_out + B_SZ * HD);
}

// Round 6
// 886.544 us; speedup vs baseline: 2.5086x; 1.1759x over previous
//
#include <hip/hip_runtime.h>
#include <cstdint>
#include <cstddef>

#define N_PTS 65536
#define B_SZ 32
#define K_FPS 8
#define GRP 512
#define NP 513
#define HD 128
#define R2C 0.04f
#define BIGF 1e10f

typedef unsigned int u32;
typedef unsigned long long u64;
using bf8  = __attribute__((ext_vector_type(8))) short;   // 8 x bf16 bits
using f32x4 = __attribute__((ext_vector_type(4))) float;

// ---- helpers ---------------------------------------------------------------
__device__ __forceinline__ unsigned short f2bf(float f) {
  u32 u = __float_as_uint(f);
  u32 r = (u + 0x7FFFu + ((u >> 16) & 1u)) >> 16;   // RNE
  return (unsigned short)r;
}
__device__ __forceinline__ float bf2f(unsigned short h) {
  return __uint_as_float(((u32)h) << 16);
}
// monotone float<->uint for atomicMax
__device__ __forceinline__ u32 xf(float v) {
  u32 u = __float_as_uint(v);
  return (u & 0x80000000u) ? ~u : (u | 0x80000000u);
}
__device__ __forceinline__ float xinv(u32 u) {
  return (u & 0x80000000u) ? __uint_as_float(u & 0x7FFFFFFFu) : __uint_as_float(~u);
}
__device__ __forceinline__ f32x4 mfma16(bf8 a, bf8 b, f32x4 c) {
  return __builtin_amdgcn_mfma_f32_16x16x32_bf16(a, b, c, 0, 0, 0);
}

// ---------------------------------------------------------------------------
// Fused init: slots (7*32 u64 = 448 u32) -> 0 ; tmaxU (4*256*128) -> 0 ;
// goutU (256*128) -> 0x00800000 (= xf(-FLT_MAX)) ; cmaxU (32*256) -> 0.
// ---------------------------------------------------------------------------
__global__ void init_all_kernel(u32* __restrict__ slots32,
                                u32* __restrict__ tmaxU,
                                u32* __restrict__ goutU,
                                u32* __restrict__ cmaxU) {
  int i = blockIdx.x * blockDim.x + threadIdx.x;
  if (i < 448) slots32[i] = 0u;
  if (i < 4 * 256 * HD) tmaxU[i] = 0u;
  if (i < 256 * HD) goutU[i] = 0x00800000u;
  if (i < B_SZ * 256) cmaxU[i] = 0u;
}

// ---------------------------------------------------------------------------
// FPS step IT (IT = 0..6): 2048 blocks (32 batches x 64 slices of 1024 pts).
// No dist buffer: recompute min over centers 0..IT from x (bitwise-identical
// fmin chain to the incremental version). Winner for center IT+1 via packed
// u64 atomicMax: key = xf(d)<<32 | (0xFFFFFFFF - idx) -> max d, min idx tie.
// ---------------------------------------------------------------------------
template <int IT>
__global__ __launch_bounds__(256) void fps_step(const float* __restrict__ x,
                                                u64* __restrict__ slots) {
  int blk = blockIdx.x;
  int b = blk >> 6, s = blk & 63;
  int tid = threadIdx.x;
  const float* xb = x + (size_t)b * N_PTS * 3;
  __shared__ float cx[8], cy[8], cz[8];
  if (tid <= IT) {
    int ci = (tid == 0) ? 0 : (int)(0xFFFFFFFFu - (u32)slots[(tid - 1) * B_SZ + b]);
    cx[tid] = xb[ci * 3 + 0];
    cy[tid] = xb[ci * 3 + 1];
    cz[tid] = xb[ci * 3 + 2];
  }
  __syncthreads();
  float best = -1.0f; int bi = 0;
  int base = s * 1024;
#pragma unroll
  for (int j = 0; j < 4; ++j) {
    int i = base + j * 256 + tid;
    float px = xb[i * 3 + 0], py = xb[i * 3 + 1], pz = xb[i * 3 + 2];
    float d = BIGF;
#pragma unroll
    for (int c = 0; c <= IT; ++c) {
      float dx = px - cx[c], dy = py - cy[c], dz = pz - cz[c];
      d = fminf(d, dx * dx + dy * dy + dz * dz);
    }
    if (d > best) { best = d; bi = i; }
  }
  for (int off = 32; off > 0; off >>= 1) {
    float ov = __shfl_down(best, off);
    int oi = __shfl_down(bi, off);
    if (ov > best || (ov == best && oi < bi)) { best = ov; bi = oi; }
  }
  __shared__ float wv[4]; __shared__ int wi[4];
  if ((tid & 63) == 0) { wv[tid >> 6] = best; wi[tid >> 6] = bi; }
  __syncthreads();
  if (tid == 0) {
    float bv = wv[0]; int bx = wi[0];
    for (int k = 1; k < 4; ++k)
      if (wv[k] > bv || (wv[k] == bv && wi[k] < bx)) { bv = wv[k]; bx = wi[k]; }
    u64 key = ((u64)xf(bv) << 32) | (u64)(0xFFFFFFFFu - (u32)bx);
    atomicMax(&slots[IT * B_SZ + b], key);
  }
}

// ---------------------------------------------------------------------------
// Ball query: 1024 threads, contiguous 64-pt range per thread, bitmask + scan.
// XCD-aware block swizzle: all 8 groups of batch b land on XCD b%8 so x is
// fetched from HBM once per XCD and re-served from that XCD's L2.
// Decodes the 8 centers from slots (center 0 = idx 0).
// ---------------------------------------------------------------------------
__global__ __launch_bounds__(1024) void ballq_kernel(const float* __restrict__ x,
                                                     const u64* __restrict__ slots,
                                                     float* __restrict__ cxyz,
                                                     float* __restrict__ grouped) {
  int i0 = blockIdx.x;
  int xcd = i0 & 7, j0 = i0 >> 3;
  int b = xcd + 8 * (j0 >> 3);
  int k = j0 & 7;
  int g = b * 8 + k;
  int tid = threadIdx.x;
  const float* xb = x + (size_t)b * N_PTS * 3;
  __shared__ int sPref[1024];
  __shared__ int s_in[GRP];
  __shared__ int s_out[GRP];
  __shared__ float sc[3];
  if (tid == 0) {
    int ci = (k == 0) ? 0 : (int)(0xFFFFFFFFu - (u32)slots[(k - 1) * B_SZ + b]);
    sc[0] = xb[ci * 3 + 0]; sc[1] = xb[ci * 3 + 1]; sc[2] = xb[ci * 3 + 2];
  }
  __syncthreads();
  float c0 = sc[0], c1 = sc[1], c2 = sc[2];
  int base = tid * 64;
  unsigned long long bm = 0ull;
  int cnt = 0;
  for (int j = 0; j < 64; ++j) {
    int i = base + j;
    float dx = xb[i * 3 + 0] - c0;
    float dy = xb[i * 3 + 1] - c1;
    float dz = xb[i * 3 + 2] - c2;
    float d = dx * dx + dy * dy + dz * dz;
    bool inr = !(d > R2C);
    if (inr) { bm |= (1ull << j); ++cnt; }
  }
  sPref[tid] = cnt;
  __syncthreads();
  for (int off = 1; off < 1024; off <<= 1) {
    int add = (tid >= off) ? sPref[tid - off] : 0;
    __syncthreads();
    sPref[tid] += add;
    __syncthreads();
  }
  int inc = sPref[tid];
  int exc = inc - cnt;
  int outExc = base - exc;
  {
    int ii = exc, oo = outExc;
    for (int j = 0; j < 64; ++j) {
      if ((bm >> j) & 1ull) { if (ii < GRP) s_in[ii] = base + j; ++ii; }
      else                  { if (oo < GRP) s_out[oo] = base + j; ++oo; }
    }
  }
  __syncthreads();
  int incnt = min(sPref[1023], GRP);
  if (tid == 0) {
    cxyz[g * 3 + 0] = c0; cxyz[g * 3 + 1] = c1; cxyz[g * 3 + 2] = c2;
    float* o0 = grouped + (size_t)g * NP * 3;
    o0[0] = c0; o0[1] = c1; o0[2] = c2;
  } else if (tid <= GRP) {
    int j = tid - 1;
    int src = (j < incnt) ? s_in[j] : s_out[j - incnt];
    float* o = grouped + ((size_t)g * NP + 1 + j) * 3;
    o[0] = xb[src * 3 + 0] - c0;
    o[1] = xb[src * 3 + 1] - c1;
    o[2] = xb[src * 3 + 2] - c2;
  }
}

// ---------------------------------------------------------------------------
// Weight prep: fp32 -> swizzled bf16 hi/lo planes.  plane[o][k ^ ((o&7)<<3)]
// ---------------------------------------------------------------------------
__global__ void wprep_kernel(const float* __restrict__ layer_w,
                             const float* __restrict__ glayer_w,
                             const float* __restrict__ conv_out_w,
                             short* __restrict__ w1h, short* __restrict__ w1l,
                             short* __restrict__ w2h, short* __restrict__ w2l,
                             short* __restrict__ coh, short* __restrict__ col_) {
  int id = blockIdx.x * blockDim.x + threadIdx.x;
  float v; short *dh, *dl; size_t dpos;
  if (id < 65536) {
    int l = id >> 14, o = (id >> 7) & 127, k = id & 127;
    v = layer_w[(size_t)l * 16384 + o * 128 + k];
    dpos = (size_t)l * 16384 + o * 128 + (k ^ ((o & 7) << 3));
    dh = w1h; dl = w1l;
  } else if (id < 131072) {
    int t = id - 65536;
    int l = t >> 14, o = (t >> 7) & 127, k = t & 127;
    v = glayer_w[(size_t)l * 32768 + o * 256 + k];
    dpos = (size_t)l * 16384 + o * 128 + (k ^ ((o & 7) << 3));
    dh = w2h; dl = w2l;
  } else if (id < 196608) {
    int t = id - 131072;
    int o = t >> 9, k = t & 511;
    v = conv_out_w[(size_t)o * 512 + k];
    dpos = (size_t)o * 512 + (k ^ ((o & 7) << 3));
    dh = coh; dl = col_;
  } else return;
  unsigned short h = f2bf(v);
  dh[dpos] = (short)h;
  dl[dpos] = (short)f2bf(v - bf2f(h));
}

// ---------------------------------------------------------------------------
// conv_in -> y0 planes (swizzled hi/lo), pad rows zeroed.
// ---------------------------------------------------------------------------
__global__ void conv_in_kernel(const float* __restrict__ gp,
                               const float* __restrict__ W,
                               const float* __restrict__ bias,
                               short* __restrict__ oh, short* __restrict__ ol,
                               int M, int Mp) {
  int idx = blockIdx.x * blockDim.x + threadIdx.x;
  if (idx >= Mp * HD) return;
  int r = idx >> 7, c = idx & 127;
  float v = 0.0f;
  if (r < M) {
    const float* p = gp + (size_t)r * 3;
    v = bias[c] + p[0] * W[c * 3 + 0] + p[1] * W[c * 3 + 1] + p[2] * W[c * 3 + 2];
    v = fmaxf(v, 0.0f);
  }
  unsigned short h = f2bf(v);
  size_t pos = (size_t)r * HD + (c ^ ((r & 7) << 3));
  oh[pos] = (short)h;
  ol[pos] = (short)f2bf(v - bf2f(h));
}

// ---------------------------------------------------------------------------
// bf16x3-split MFMA GEMM.  out[M][128] = f(A[M][128] @ W^T)
// 256 threads / 4 waves, tile 128x128, wave-tile 64x64, BK=64, LDS 64 KiB
// -> 2 blocks/CU for stage/compute overlap.
// MODE 0: +bias[col], relu, write planes, atomicMax redU[grp][col]
// MODE 1: +gvec[grp][col], relu, write planes
// MODE 2: K=512 over 4 feat buffers, no bias/relu, atomicMax redU[grp][col]
// ---------------------------------------------------------------------------
template <int MODE>
__global__ __launch_bounds__(256, 2) void mfgemm(
    const short* __restrict__ a0h, const short* __restrict__ a0l,
    const short* __restrict__ a1h, const short* __restrict__ a1l,
    const short* __restrict__ a2h, const short* __restrict__ a2l,
    const short* __restrict__ a3h, const short* __restrict__ a3l,
    const short* __restrict__ wh, const short* __restrict__ wl,
    int wRowShorts,
    const float* __restrict__ bias,
    short* __restrict__ oh, short* __restrict__ ol,
    u32* __restrict__ redU,
    int M) {
  __shared__ short lds[4][128][64];       // Ah, Al, Wh, Wl (64 KiB)
  const int tid = threadIdx.x;
  const int lane = tid & 63, w = tid >> 6;
  const int wr = w >> 1, wc = w & 1;      // 2x2 wave grid, 64x64 wave-tile
  const int m0 = blockIdx.x * 128;
  const int wRB = wRowShorts * 2;

  f32x4 acc[4][4];
#pragma unroll
  for (int i = 0; i < 4; ++i)
#pragma unroll
    for (int j = 0; j < 4; ++j) acc[i][j] = (f32x4){0.f, 0.f, 0.f, 0.f};

  const int NH = (MODE == 2) ? 8 : 2;     // K-halves of 64
  const short* ahp[4] = {a0h, a1h, a2h, a3h};
  const short* alp[4] = {a0l, a1l, a2l, a3l};

#pragma unroll
  for (int hf = 0; hf < NH; ++hf) {
    {
      const char* pAh = (const char*)ahp[hf >> 1] + (size_t)m0 * 256 + (hf & 1) * 128;
      const char* pAl = (const char*)alp[hf >> 1] + (size_t)m0 * 256 + (hf & 1) * 128;
      const char* pWh = (const char*)wh + hf * 128;
      const char* pWl = (const char*)wl + hf * 128;
#pragma unroll
      for (int i = 0; i < 16; ++i) {
        int c2 = i * 256 + tid;           // chunk id 0..4095
        int plane = c2 >> 10;
        int idx = c2 & 1023;
        int row = idx >> 3, ch = idx & 7;
        const char* s = (plane == 0) ? pAh : (plane == 1) ? pAl
                       : (plane == 2) ? pWh : pWl;
        int rb = (plane < 2) ? 256 : wRB;
        const char* src = s + (size_t)row * rb + ch * 16;
        void* dst = (char*)lds + (size_t)c2 * 16;
        __builtin_amdgcn_global_load_lds(
            (const __attribute__((address_space(1))) u32*)src,
            (__attribute__((address_space(3))) u32*)dst, 16, 0, 0);
      }
    }
    __syncthreads();
#pragma unroll
    for (int kk = 0; kk < 2; ++kk) {
      int k0 = kk * 32 + (lane >> 4) * 8;
      bf8 afh[4], afl[4], bfh[4], bfl[4];
#pragma unroll
      for (int rt = 0; rt < 4; ++rt) {
        int row = wr * 64 + rt * 16 + (lane & 15);
        int kp = k0 ^ ((row & 7) << 3);
        afh[rt] = *(const bf8*)&lds[0][row][kp];
        afl[rt] = *(const bf8*)&lds[1][row][kp];
      }
#pragma unroll
      for (int ct = 0; ct < 4; ++ct) {
        int orow = wc * 64 + ct * 16 + (lane & 15);
        int kp = k0 ^ ((orow & 7) << 3);
        bfh[ct] = *(const bf8*)&lds[2][orow][kp];
        bfl[ct] = *(const bf8*)&lds[3][orow][kp];
      }
#pragma unroll
      for (int rt = 0; rt < 4; ++rt)
#pragma unroll
        for (int ct = 0; ct < 4; ++ct) {
          acc[rt][ct] = mfma16(afh[rt], bfh[ct], acc[rt][ct]);
          acc[rt][ct] = mfma16(afh[rt], bfl[ct], acc[rt][ct]);
          acc[rt][ct] = mfma16(afl[rt], bfh[ct], acc[rt][ct]);
        }
    }
    if (hf + 1 < NH) __syncthreads();
  }

  // epilogue
#pragma unroll
  for (int ct = 0; ct < 4; ++ct) {
    int col = wc * 64 + ct * 16 + (lane & 15);
    int curGrp = -1;
    u32 curKey = 0;
#pragma unroll
    for (int rt = 0; rt < 4; ++rt) {
      int rbase = m0 + wr * 64 + rt * 16 + ((lane >> 4) << 2);
#pragma unroll
      for (int reg = 0; reg < 4; ++reg) {
        int row = rbase + reg;
        float v = acc[rt][ct][reg];
        if (MODE == 0) v += bias[col];
        if (MODE == 1) v += bias[(row / 513) * HD + col];
        if (MODE != 2) {
          v = fmaxf(v, 0.0f);
          unsigned short h = f2bf(v);
          unsigned short l2 = f2bf(v - bf2f(h));
          size_t pos = (size_t)row * HD + (col ^ ((row & 7) << 3));
          oh[pos] = (short)h;
          ol[pos] = (short)l2;
        }
        if (MODE == 0 || MODE == 2) {
          if (row < M) {
            int gg = row / 513;
            u32 key = xf(v);
            if (gg != curGrp) {
              if (curGrp >= 0) atomicMax(&redU[curGrp * HD + col], curKey);
              curGrp = gg; curKey = key;
            } else {
              curKey = max(curKey, key);
            }
          }
        }
      }
    }
    if ((MODE == 0 || MODE == 2) && curGrp >= 0)
      atomicMax(&redU[curGrp * HD + col], curKey);
  }
}

// gvec[g][c] = gb[c] + sum_j tmax[g][j] * gw[c][128+j]
__global__ void gvec_kernel(const u32* __restrict__ tmaxU, const float* __restrict__ gw,
                            const float* __restrict__ gb, float* __restrict__ gvec) {
  int g = blockIdx.x, c = threadIdx.x;
  __shared__ float sm[HD];
  sm[c] = xinv(tmaxU[g * HD + c]);
  __syncthreads();
  const float* wr = gw + (size_t)c * (2 * HD) + HD;
  float s = gb[c];
  for (int j = 0; j < HD; ++j) s += sm[j] * wr[j];
  gvec[g * HD + c] = s;
}

__global__ void batchmax_kernel(const u32* __restrict__ goutU,
                                const float* __restrict__ bout,
                                float* __restrict__ out) {
  int b = blockIdx.x, c = threadIdx.x;
  float m = -3.4e38f;
  for (int k = 0; k < K_FPS; ++k) m = fmaxf(m, xinv(goutU[(size_t)(b * K_FPS + k) * HD + c]));
  out[b * HD + c] = m + bout[c];
}

// ---------------------------------------------------------------------------
// Centroid MLP path: cpathA = one block per (b,k) centroid, atomicMax into
// cmaxU; cpathB = final matvec + LN per batch.
// ---------------------------------------------------------------------------
__device__ __forceinline__ void block_ln(float* h, int n, const float* __restrict__ gam,
                                         const float* __restrict__ bet, float* red,
                                         int tid, bool relu) {
  float v = (tid < n) ? h[tid] : 0.0f;
  red[tid] = v;
  __syncthreads();
  for (int s = 128; s > 0; s >>= 1) { if (tid < s) red[tid] += red[tid + s]; __syncthreads(); }
  float mean = red[0] / n;
  __syncthreads();
  float d = (tid < n) ? (h[tid] - mean) : 0.0f;
  red[tid] = d * d;
  __syncthreads();
  for (int s = 128; s > 0; s >>= 1) { if (tid < s) red[tid] += red[tid + s]; __syncthreads(); }
  float var = red[0] / n;
  __syncthreads();
  if (tid < n) {
    float o = (h[tid] - mean) / sqrtf(var + 1e-5f) * gam[tid] + bet[tid];
    if (relu) o = fmaxf(o, 0.0f);
    h[tid] = o;
  }
  __syncthreads();
}

__global__ __launch_bounds__(256) void cpathA_kernel(const float* __restrict__ cxyz,
    const float* __restrict__ w0, const float* __restrict__ b0,
    const float* __restrict__ g0, const float* __restrict__ e0,
    const float* __restrict__ w1, const float* __restrict__ b1,
    const float* __restrict__ g1, const float* __restrict__ e1,
    const float* __restrict__ w2, const float* __restrict__ b2,
    const float* __restrict__ g2, const float* __restrict__ e2,
    u32* __restrict__ cmaxU) {
  int g = blockIdx.x, b = g >> 3, tid = threadIdx.x;
  __shared__ float h[256];
  __shared__ float hb[256];
  __shared__ float red[256];
  const float* cp = cxyz + (size_t)g * 3;
  float p0 = cp[0], p1 = cp[1], p2 = cp[2];
  if (tid < 64)
    h[tid] = b0[tid] + p0 * w0[tid * 3 + 0] + p1 * w0[tid * 3 + 1] + p2 * w0[tid * 3 + 2];
  __syncthreads();
  block_ln(h, 64, g0, e0, red, tid, true);
  if (tid < 128) {
    float s = b1[tid];
    const float* wr = w1 + (size_t)tid * 64;
    for (int j = 0; j < 64; ++j) s += h[j] * wr[j];
    hb[tid] = s;
  }
  __syncthreads();
  block_ln(hb, 128, g1, e1, red, tid, true);
  {
    float s = b2[tid];
    const float* wr = w2 + (size_t)tid * 128;
    for (int j = 0; j < 128; ++j) s += hb[j] * wr[j];
    __syncthreads();
    h[tid] = s;
  }
  __syncthreads();
  block_ln(h, 256, g2, e2, red, tid, true);
  atomicMax(&cmaxU[b * 256 + tid], xf(h[tid]));
}

__global__ __launch_bounds__(256) void cpathB_kernel(const u32* __restrict__ cmaxU,
    const float* __restrict__ fw, const float* __restrict__ fb,
    const float* __restrict__ fg, const float* __restrict__ fe,
    float* __restrict__ out) {
  int b = blockIdx.x, tid = threadIdx.x;
  __shared__ float cm[256];
  __shared__ float h[256];
  __shared__ float red[256];
  cm[tid] = xinv(cmaxU[b * 256 + tid]);
  __syncthreads();
  if (tid < 128) {
    float s = fb[tid];
    const float* wr = fw + (size_t)tid * 256;
    for (int j = 0; j < 256; ++j) s += cm[j] * wr[j];
    h[tid] = s;
  }
  __syncthreads();
  block_ln(h, 128, fg, fe, red, tid, false);
  if (tid < 128) out[b * HD + tid] = h[tid];
}

// ---------------------------------------------------------------------------
extern "C" void kernel_launch(void* const* d_in, const int* in_sizes, int n_in,
                              void* d_out, int out_size, void* d_ws, size_t ws_size,
                              hipStream_t stream) {
  (void)in_sizes; (void)n_in; (void)out_size;
  const float* x          = (const float*)d_in[0];
  const float* conv_in_w  = (const float*)d_in[1];
  const float* conv_in_b  = (const float*)d_in[2];
  const float* layer_w    = (const float*)d_in[3];
  const float* layer_b    = (const float*)d_in[4];
  const float* glayer_w   = (const float*)d_in[5];
  const float* glayer_b   = (const float*)d_in[6];
  const float* conv_out_w = (const float*)d_in[7];
  const float* conv_out_b = (const float*)d_in[8];
  const float* mlp_w0 = (const float*)d_in[9];
  const float* mlp_b0 = (const float*)d_in[10];
  const float* ln0_g  = (const float*)d_in[11];
  const float* ln0_b  = (const float*)d_in[12];
  const float* mlp_w1 = (const float*)d_in[13];
  const float* mlp_b1 = (const float*)d_in[14];
  const float* ln1_g  = (const float*)d_in[15];
  const float* ln1_b  = (const float*)d_in[16];
  const float* mlp_w2 = (const float*)d_in[17];
  const float* mlp_b2 = (const float*)d_in[18];
  const float* ln2_g  = (const float*)d_in[19];
  const float* ln2_b  = (const float*)d_in[20];
  const float* fp_w   = (const float*)d_in[21];
  const float* fp_b   = (const float*)d_in[22];
  const float* fp_ln_g = (const float*)d_in[23];
  const float* fp_ln_b = (const float*)d_in[24];

  char* ws = (char*)d_ws;
  size_t off = 0;
  auto carve = [&](size_t bytes) -> void* {
    void* p = ws + off;
    off += (bytes + 255) & ~(size_t)255;
    return p;
  };
  u64* slots   = (u64*)carve(7 * B_SZ * 8);
  float* cxyz  = (float*)carve(256 * 3 * 4);
  float* grouped = (float*)carve((size_t)256 * NP * 3 * 4);
  u32* goutU   = (u32*)carve(256 * HD * 4);
  u32* tmaxU   = (u32*)carve(4 * 256 * HD * 4);    // per-layer, all groups
  float* gvec  = (float*)carve(257 * HD * 4);
  u32* cmaxU   = (u32*)carve(B_SZ * 256 * 4);
  short* w1h = (short*)carve(4 * 16384 * 2);
  short* w1l = (short*)carve(4 * 16384 * 2);
  short* w2h = (short*)carve(4 * 16384 * 2);
  short* w2l = (short*)carve(4 * 16384 * 2);
  short* coh = (short*)carve(65536 * 2);
  short* col_ = (short*)carve(65536 * 2);
  size_t fixed = off;

  int C = 8;
  const int cands[5] = {128, 64, 32, 16, 8};   // prefer 128: fewer dispatches, still ~L3-resident
  for (int ci = 0; ci < 5; ++ci) {
    int Cc = cands[ci];
    size_t Mp = ((size_t)(513 * Cc + 127) / 128) * 128;
    size_t need = fixed + 12 * ((Mp * HD * 2 + 255) & ~(size_t)255) + 65536;
    if (need <= ws_size) { C = Cc; break; }
  }
  int Mp = (int)(((size_t)(513 * C + 127) / 128) * 128);
  size_t planeB = (size_t)Mp * HD * 2;
  short* y0h = (short*)carve(planeB); short* y0l = (short*)carve(planeB);
  short* th  = (short*)carve(planeB); short* tl  = (short*)carve(planeB);
  short* fh[4]; short* fl[4];
  for (int l = 0; l < 4; ++l) { fh[l] = (short*)carve(planeB); fl[l] = (short*)carve(planeB); }

  init_all_kernel<<<(4 * 256 * HD + 255) / 256, 256, 0, stream>>>(
      (u32*)slots, tmaxU, goutU, cmaxU);

  fps_step<0><<<2048, 256, 0, stream>>>(x, slots);
  fps_step<1><<<2048, 256, 0, stream>>>(x, slots);
  fps_step<2><<<2048, 256, 0, stream>>>(x, slots);
  fps_step<3><<<2048, 256, 0, stream>>>(x, slots);
  fps_step<4><<<2048, 256, 0, stream>>>(x, slots);
  fps_step<5><<<2048, 256, 0, stream>>>(x, slots);
  fps_step<6><<<2048, 256, 0, stream>>>(x, slots);

  ballq_kernel<<<256, 1024, 0, stream>>>(x, slots, cxyz, grouped);
  wprep_kernel<<<768, 256, 0, stream>>>(layer_w, glayer_w, conv_out_w,
                                        w1h, w1l, w2h, w2l, coh, col_);

  int M = C * 513;
  int nb = Mp / 128;
  for (int g0 = 0; g0 < 256; g0 += C) {
    conv_in_kernel<<<(Mp * HD + 255) / 256, 256, 0, stream>>>(
        grouped + (size_t)g0 * NP * 3, conv_in_w, conv_in_b, y0h, y0l, M, Mp);
    const short* inH = y0h; const short* inL = y0l;
    for (int l = 0; l < 4; ++l) {
      u32* tmaxL = tmaxU + (size_t)l * 256 * HD + (size_t)g0 * HD;
      mfgemm<0><<<nb, 256, 0, stream>>>(
          inH, inL, inH, inL, inH, inL, inH, inL,
          w1h + (size_t)l * 16384, w1l + (size_t)l * 16384, 128,
          layer_b + l * HD, th, tl, tmaxL, M);
      gvec_kernel<<<C, HD, 0, stream>>>(tmaxL, glayer_w + (size_t)l * HD * 2 * HD,
                                        glayer_b + l * HD, gvec);
      mfgemm<1><<<nb, 256, 0, stream>>>(
          th, tl, th, tl, th, tl, th, tl,
          w2h + (size_t)l * 16384, w2l + (size_t)l * 16384, 128,
          gvec, fh[l], fl[l], nullptr, M);
      inH = fh[l]; inL = fl[l];
    }
    mfgemm<2><<<nb, 256, 0, stream>>>(
        fh[0], fl[0], fh[1], fl[1], fh[2], fl[2], fh[3], fl[3],
        coh, col_, 512, nullptr, nullptr, nullptr, goutU + (size_t)g0 * HD, M);
  }
  batchmax_kernel<<<B_SZ, HD, 0, stream>>>(goutU, conv_out_b, (float*)d_out);
  cpathA_kernel<<<256, 256, 0, stream>>>(cxyz,
      mlp_w0, mlp_b0, ln0_g, ln0_b,
      mlp_w1, mlp_b1, ln1_g, ln1_b,
      mlp_w2, mlp_b2, ln2_g, ln2_b, cmaxU);
  cpathB_kernel<<<B_SZ, 256, 0, stream>>>(cmaxU, fp_w, fp_b, fp_ln_g, fp_ln_b,
                                          (float*)d_out + B_SZ * HD);
}

// Round 11
// 779.217 us; speedup vs baseline: 2.8541x; 1.1377x over previous
//
#include <hip/hip_runtime.h>
#include <cstdint>
#include <cstddef>

#define N_PTS 65536
#define B_SZ 32
#define K_FPS 8
#define GRP 512
#define NP 513
#define HD 128
#define R2C 0.04f
#define BIGF 1e10f

typedef unsigned int u32;
typedef unsigned long long u64;
using bf8   = __attribute__((ext_vector_type(8))) short;   // 8 x bf16 bits
using s8v   = __attribute__((ext_vector_type(8))) short;
using f32x4 = __attribute__((ext_vector_type(4))) float;
using i32x4 = __attribute__((ext_vector_type(4))) int;

// ---- helpers ---------------------------------------------------------------
__device__ __forceinline__ unsigned short f2bf(float f) {
  u32 u = __float_as_uint(f);
  u32 r = (u + 0x7FFFu + ((u >> 16) & 1u)) >> 16;   // RNE
  return (unsigned short)r;
}
__device__ __forceinline__ float bf2f(unsigned short h) {
  return __uint_as_float(((u32)h) << 16);
}
// monotone float<->uint for atomicMax
__device__ __forceinline__ u32 xf(float v) {
  u32 u = __float_as_uint(v);
  return (u & 0x80000000u) ? ~u : (u | 0x80000000u);
}
__device__ __forceinline__ float xinv(u32 u) {
  return (u & 0x80000000u) ? __uint_as_float(u & 0x7FFFFFFFu) : __uint_as_float(~u);
}
__device__ __forceinline__ f32x4 mfma16(bf8 a, bf8 b, f32x4 c) {
  return __builtin_amdgcn_mfma_f32_16x16x32_bf16(a, b, c, 0, 0, 0);
}

// ---------------------------------------------------------------------------
// Fused init: slots -> 0 ; tmaxU (4*256*128) -> 0 ;
// goutU (256*128) -> 0x00800000 (= xf(-FLT_MAX)) ; cmaxU (32*256) -> 0.
// ---------------------------------------------------------------------------
__global__ void init_all_kernel(u32* __restrict__ slots32,
                                u32* __restrict__ tmaxU,
                                u32* __restrict__ goutU,
                                u32* __restrict__ cmaxU) {
  int i = blockIdx.x * blockDim.x + threadIdx.x;
  if (i < 448) slots32[i] = 0u;
  if (i < 4 * 256 * HD) tmaxU[i] = 0u;
  if (i < 256 * HD) goutU[i] = 0x00800000u;
  if (i < B_SZ * 256) cmaxU[i] = 0u;
}

// ---------------------------------------------------------------------------
// FPS step IT (0..6): 2048 blocks, XCD-stable mapping: block -> region p so
// region p always lands on XCD p/256; each XCD re-reads the same 3.1 MB of x
// from its own L2 across all 7 steps.  Winner via packed u64 atomicMax.
// ---------------------------------------------------------------------------
template <int IT>
__global__ __launch_bounds__(256) void fps_step(const float* __restrict__ x,
                                                u64* __restrict__ slots) {
  int p = (blockIdx.x & 7) * 256 + (blockIdx.x >> 3);
  int b = p >> 6, s = p & 63;
  int tid = threadIdx.x;
  const float* xb = x + (size_t)b * N_PTS * 3;
  __shared__ float cx[8], cy[8], cz[8];
  if (tid <= IT) {
    int ci = (tid == 0) ? 0 : (int)(0xFFFFFFFFu - (u32)slots[(tid - 1) * B_SZ + b]);
    cx[tid] = xb[ci * 3 + 0];
    cy[tid] = xb[ci * 3 + 1];
    cz[tid] = xb[ci * 3 + 2];
  }
  __syncthreads();
  float best = -1.0f; int bi = 0;
  int base = s * 1024;
#pragma unroll
  for (int j = 0; j < 4; ++j) {
    int i = base + j * 256 + tid;
    float px = xb[i * 3 + 0], py = xb[i * 3 + 1], pz = xb[i * 3 + 2];
    float d = BIGF;
#pragma unroll
    for (int c = 0; c <= IT; ++c) {
      float dx = px - cx[c], dy = py - cy[c], dz = pz - cz[c];
      d = fminf(d, dx * dx + dy * dy + dz * dz);
    }
    if (d > best) { best = d; bi = i; }
  }
  for (int off = 32; off > 0; off >>= 1) {
    float ov = __shfl_down(best, off);
    int oi = __shfl_down(bi, off);
    if (ov > best || (ov == best && oi < bi)) { best = ov; bi = oi; }
  }
  __shared__ float wv[4]; __shared__ int wi[4];
  if ((tid & 63) == 0) { wv[tid >> 6] = best; wi[tid >> 6] = bi; }
  __syncthreads();
  if (tid == 0) {
    float bv = wv[0]; int bx = wi[0];
    for (int k = 1; k < 4; ++k)
      if (wv[k] > bv || (wv[k] == bv && wi[k] < bx)) { bv = wv[k]; bx = wi[k]; }
    u64 key = ((u64)xf(bv) << 32) | (u64)(0xFFFFFFFFu - (u32)bx);
    atomicMax(&slots[IT * B_SZ + b], key);
  }
}

// ---------------------------------------------------------------------------
// Ball query: mapping aligned with fps (batch b on XCD b/4) so x is L2-hot.
// ---------------------------------------------------------------------------
__global__ __launch_bounds__(1024) void ballq_kernel(const float* __restrict__ x,
                                                     const u64* __restrict__ slots,
                                                     float* __restrict__ cxyz,
                                                     float* __restrict__ grouped) {
  int blk = blockIdx.x;
  int xcd = blk & 7, j0 = blk >> 3;          // j0 in [0,32)
  int b = xcd * 4 + (j0 >> 3);
  int k = j0 & 7;
  int g = b * 8 + k;
  int tid = threadIdx.x;
  const float* xb = x + (size_t)b * N_PTS * 3;
  __shared__ int sPref[1024];
  __shared__ int s_in[GRP];
  __shared__ int s_out[GRP];
  __shared__ float sc[3];
  if (tid == 0) {
    int ci = (k == 0) ? 0 : (int)(0xFFFFFFFFu - (u32)slots[(k - 1) * B_SZ + b]);
    sc[0] = xb[ci * 3 + 0]; sc[1] = xb[ci * 3 + 1]; sc[2] = xb[ci * 3 + 2];
  }
  __syncthreads();
  float c0 = sc[0], c1 = sc[1], c2 = sc[2];
  int base = tid * 64;
  unsigned long long bm = 0ull;
  int cnt = 0;
  for (int j = 0; j < 64; ++j) {
    int i = base + j;
    float dx = xb[i * 3 + 0] - c0;
    float dy = xb[i * 3 + 1] - c1;
    float dz = xb[i * 3 + 2] - c2;
    float d = dx * dx + dy * dy + dz * dz;
    bool inr = !(d > R2C);
    if (inr) { bm |= (1ull << j); ++cnt; }
  }
  sPref[tid] = cnt;
  __syncthreads();
  for (int off = 1; off < 1024; off <<= 1) {
    int add = (tid >= off) ? sPref[tid - off] : 0;
    __syncthreads();
    sPref[tid] += add;
    __syncthreads();
  }
  int inc = sPref[tid];
  int exc = inc - cnt;
  int outExc = base - exc;
  {
    int ii = exc, oo = outExc;
    for (int j = 0; j < 64; ++j) {
      if ((bm >> j) & 1ull) { if (ii < GRP) s_in[ii] = base + j; ++ii; }
      else                  { if (oo < GRP) s_out[oo] = base + j; ++oo; }
    }
  }
  __syncthreads();
  int incnt = min(sPref[1023], GRP);
  if (tid == 0) {
    cxyz[g * 3 + 0] = c0; cxyz[g * 3 + 1] = c1; cxyz[g * 3 + 2] = c2;
    float* o0 = grouped + (size_t)g * NP * 3;
    o0[0] = c0; o0[1] = c1; o0[2] = c2;
  } else if (tid <= GRP) {
    int j = tid - 1;
    int src = (j < incnt) ? s_in[j] : s_out[j - incnt];
    float* o = grouped + ((size_t)g * NP + 1 + j) * 3;
    o[0] = xb[src * 3 + 0] - c0;
    o[1] = xb[src * 3 + 1] - c1;
    o[2] = xb[src * 3 + 2] - c2;
  }
}

// ---------------------------------------------------------------------------
// Weight prep: fp32 -> swizzled bf16 hi/lo planes.  plane[o][k ^ ((o&7)<<3)]
// ---------------------------------------------------------------------------
__global__ void wprep_kernel(const float* __restrict__ layer_w,
                             const float* __restrict__ glayer_w,
                             const float* __restrict__ conv_out_w,
                             short* __restrict__ w1h, short* __restrict__ w1l,
                             short* __restrict__ w2h, short* __restrict__ w2l,
                             short* __restrict__ coh, short* __restrict__ col_) {
  int id = blockIdx.x * blockDim.x + threadIdx.x;
  float v; short *dh, *dl; size_t dpos;
  if (id < 65536) {
    int l = id >> 14, o = (id >> 7) & 127, k = id & 127;
    v = layer_w[(size_t)l * 16384 + o * 128 + k];
    dpos = (size_t)l * 16384 + o * 128 + (k ^ ((o & 7) << 3));
    dh = w1h; dl = w1l;
  } else if (id < 131072) {
    int t = id - 65536;
    int l = t >> 14, o = (t >> 7) & 127, k = t & 127;
    v = glayer_w[(size_t)l * 32768 + o * 256 + k];
    dpos = (size_t)l * 16384 + o * 128 + (k ^ ((o & 7) << 3));
    dh = w2h; dl = w2l;
  } else if (id < 196608) {
    int t = id - 131072;
    int o = t >> 9, k = t & 511;
    v = conv_out_w[(size_t)o * 512 + k];
    dpos = (size_t)o * 512 + (k ^ ((o & 7) << 3));
    dh = coh; dl = col_;
  } else return;
  unsigned short h = f2bf(v);
  dh[dpos] = (short)h;
  dl[dpos] = (short)f2bf(v - bf2f(h));
}

// ---------------------------------------------------------------------------
// bf16x3-split MFMA GEMM.  Tile 64 rows x 128 cols, BK=64, 256 thr / 4 waves,
// LDS 48 KiB -> 3 blocks/CU.  M = C*513 divisible by 64 -> no pad rows.
// MODE 0: A from planes; +bias[col], relu, store planes, atomicMax tmax
// MODE 1: A from planes; +gvec[grp][col], relu, store planes
// MODE 2: K=512 over 4 plane-pairs; raw, atomicMax gout
// MODE 3: layer-0: A computed in-kernel from grouped pts (fused conv_in);
//         epilogue same as MODE 0.
// Stores go through an LDS image -> full-line coalesced global writes (no RFO).
// ---------------------------------------------------------------------------
template <int MODE>
__global__ __launch_bounds__(256, 3) void mfgemm(
    const short* __restrict__ a0h, const short* __restrict__ a0l,
    const short* __restrict__ a1h, const short* __restrict__ a1l,
    const short* __restrict__ a2h, const short* __restrict__ a2l,
    const short* __restrict__ a3h, const short* __restrict__ a3l,
    const short* __restrict__ wh, const short* __restrict__ wl,
    int wRowShorts,
    const float* __restrict__ bias,
    const float* __restrict__ cw, const float* __restrict__ cb,
    const float* __restrict__ gp,
    short* __restrict__ oh, short* __restrict__ ol,
    u32* __restrict__ redU, int M) {
  __shared__ alignas(16) short ldsA[2][64][64];     // 16 KiB
  __shared__ alignas(16) short ldsW[2][128][64];    // 32 KiB
  const int tid = threadIdx.x;
  const int lane = tid & 63, w = tid >> 6;
  const int wr = w >> 1, wc = w & 1;                // 2x2 wave grid, 32x64 tiles
  const int m0 = blockIdx.x * 64;
  const int wRB = wRowShorts * 2;                   // W row bytes

  f32x4 acc[2][4];
#pragma unroll
  for (int i = 0; i < 2; ++i)
#pragma unroll
    for (int j = 0; j < 4; ++j) acc[i][j] = (f32x4){0.f, 0.f, 0.f, 0.f};

  const int NH = (MODE == 2) ? 8 : 2;
  const short* ahp[4] = {a0h, a1h, a2h, a3h};
  const short* alp[4] = {a0l, a1l, a2l, a3l};

  float gx = 0.f, gy = 0.f, gz = 0.f;
  if (MODE == 3) {
    int row = m0 + (tid >> 2);
    if (row < M) { gx = gp[row * 3]; gy = gp[row * 3 + 1]; gz = gp[row * 3 + 2]; }
  }

  for (int hf = 0; hf < NH; ++hf) {
    if (MODE == 3) {
      // W staging first (loads in flight under the VALU conv compute)
#pragma unroll
      for (int i = 0; i < 8; ++i) {
        int c2 = i * 256 + tid;                 // 2048 chunks
        int plane = c2 >> 10, idx = c2 & 1023;
        int row = idx >> 3, ch = idx & 7;
        const char* s = plane ? (const char*)wl : (const char*)wh;
        const char* src = s + (size_t)row * wRB + hf * 128 + ch * 16;
        void* dst = (char*)ldsW[plane] + (size_t)idx * 16;
        __builtin_amdgcn_global_load_lds(
            (const __attribute__((address_space(1))) u32*)src,
            (__attribute__((address_space(3))) u32*)dst, 16, 0, 0);
      }
      // compute A half: row r = tid>>2, cols [hf*64 + q*16, +16)
      int r = tid >> 2, q = tid & 3;
      bool real = (m0 + r) < M;
#pragma unroll
      for (int jj = 0; jj < 2; ++jj) {
        short hbuf[8], lbuf[8];
#pragma unroll
        for (int j = 0; j < 8; ++j) {
          int c = hf * 64 + q * 16 + jj * 8 + j;
          float v = 0.f;
          if (real)
            v = fmaxf(cb[c] + gx * cw[c * 3] + gy * cw[c * 3 + 1] + gz * cw[c * 3 + 2], 0.f);
          unsigned short hh = f2bf(v);
          hbuf[j] = (short)hh;
          lbuf[j] = (short)f2bf(v - bf2f(hh));
        }
        int pos = (q * 16 + jj * 8) ^ ((r & 7) << 3);
        *(s8v*)&ldsA[0][r][pos] = *(const s8v*)hbuf;
        *(s8v*)&ldsA[1][r][pos] = *(const s8v*)lbuf;
      }
    } else {
      // 3072 chunks: A planes 2x512, W planes 2x1024
#pragma unroll
      for (int i = 0; i < 12; ++i) {
        int c2 = i * 256 + tid;
        const char* src;
        void* dst;
        if (c2 < 1024) {
          int plane = c2 >> 9, idx = c2 & 511;
          int row = idx >> 3, ch = idx & 7;
          const char* s = plane ? (const char*)alp[hf >> 1] : (const char*)ahp[hf >> 1];
          src = s + (size_t)(m0 + row) * 256 + (hf & 1) * 128 + ch * 16;
          dst = (char*)ldsA[plane] + (size_t)idx * 16;
        } else {
          int t = c2 - 1024;
          int plane = t >> 10, idx = t & 1023;
          int row = idx >> 3, ch = idx & 7;
          const char* s = plane ? (const char*)wl : (const char*)wh;
          src = s + (size_t)row * wRB + hf * 128 + ch * 16;
          dst = (char*)ldsW[plane] + (size_t)idx * 16;
        }
        __builtin_amdgcn_global_load_lds(
            (const __attribute__((address_space(1))) u32*)src,
            (__attribute__((address_space(3))) u32*)dst, 16, 0, 0);
      }
    }
    __syncthreads();
#pragma unroll
    for (int kk = 0; kk < 2; ++kk) {
      int k0 = kk * 32 + (lane >> 4) * 8;
      bf8 afh[2], afl[2], bfh[4], bfl[4];
#pragma unroll
      for (int rt = 0; rt < 2; ++rt) {
        int row = wr * 32 + rt * 16 + (lane & 15);
        int kp = k0 ^ ((row & 7) << 3);
        afh[rt] = *(const bf8*)&ldsA[0][row][kp];
        afl[rt] = *(const bf8*)&ldsA[1][row][kp];
      }
#pragma unroll
      for (int ct = 0; ct < 4; ++ct) {
        int orow = wc * 64 + ct * 16 + (lane & 15);
        int kp = k0 ^ ((orow & 7) << 3);
        bfh[ct] = *(const bf8*)&ldsW[0][orow][kp];
        bfl[ct] = *(const bf8*)&ldsW[1][orow][kp];
      }
#pragma unroll
      for (int rt = 0; rt < 2; ++rt)
#pragma unroll
        for (int ct = 0; ct < 4; ++ct) {
          acc[rt][ct] = mfma16(afh[rt], bfh[ct], acc[rt][ct]);
          acc[rt][ct] = mfma16(afh[rt], bfl[ct], acc[rt][ct]);
          acc[rt][ct] = mfma16(afl[rt], bfh[ct], acc[rt][ct]);
        }
    }
    __syncthreads();
  }

  // ---- epilogue ----
  constexpr bool DO_STORE = (MODE != 2);
  constexpr bool DO_RED   = (MODE != 1);
  short* imgH = (short*)ldsA;                      // 64x128 shorts = 16 KiB
  short* imgL = (short*)ldsW;                      // (first 16 KiB of ldsW)
#pragma unroll
  for (int ct = 0; ct < 4; ++ct) {
    int col = wc * 64 + ct * 16 + (lane & 15);
    int curGrp = -1;
    u32 curKey = 0;
#pragma unroll
    for (int rt = 0; rt < 2; ++rt) {
      int rb = wr * 32 + rt * 16 + ((lane >> 4) << 2);
#pragma unroll
      for (int reg = 0; reg < 4; ++reg) {
        int lrow = rb + reg;
        int row = m0 + lrow;
        float v = acc[rt][ct][reg];
        if (MODE == 0 || MODE == 3) v += bias[col];
        if (MODE == 1) v += bias[(row / 513) * HD + col];
        if (MODE != 2) v = fmaxf(v, 0.0f);
        if (DO_STORE) {
          unsigned short hh = f2bf(v);
          int pos = lrow * 128 + (col ^ ((lrow & 7) << 3));
          imgH[pos] = (short)hh;
          imgL[pos] = (short)f2bf(v - bf2f(hh));
        }
        if (DO_RED && row < M) {
          int gg = row / 513;
          u32 key = xf(v);
          if (gg != curGrp) {
            if (curGrp >= 0) atomicMax(&redU[curGrp * HD + col], curKey);
            curGrp = gg; curKey = key;
          } else {
            curKey = max(curKey, key);
          }
        }
      }
    }
    if (DO_RED && curGrp >= 0) atomicMax(&redU[curGrp * HD + col], curKey);
  }
  if (DO_STORE) {
    __syncthreads();
    char* dH = (char*)oh + (size_t)m0 * 256;
    char* dL = (char*)ol + (size_t)m0 * 256;
#pragma unroll
    for (int i = 0; i < 4; ++i) {
      int idx = i * 256 + tid;
      *(i32x4*)(dH + (size_t)idx * 16) = *(const i32x4*)((const char*)imgH + (size_t)idx * 16);
      *(i32x4*)(dL + (size_t)idx * 16) = *(const i32x4*)((const char*)imgL + (size_t)idx * 16);
    }
  }
}

// gvec[g][c] = gb[c] + sum_j tmax[g][j] * gw[c][128+j]
__global__ void gvec_kernel(const u32* __restrict__ tmaxU, const float* __restrict__ gw,
                            const float* __restrict__ gb, float* __restrict__ gvec) {
  int g = blockIdx.x, c = threadIdx.x;
  __shared__ float sm[HD];
  sm[c] = xinv(tmaxU[g * HD + c]);
  __syncthreads();
  const float* wr = gw + (size_t)c * (2 * HD) + HD;
  float s = gb[c];
  for (int j = 0; j < HD; ++j) s += sm[j] * wr[j];
  gvec[g * HD + c] = s;
}

__global__ void batchmax_kernel(const u32* __restrict__ goutU,
                                const float* __restrict__ bout,
                                float* __restrict__ out) {
  int b = blockIdx.x, c = threadIdx.x;
  float m = -3.4e38f;
  for (int k = 0; k < K_FPS; ++k) m = fmaxf(m, xinv(goutU[(size_t)(b * K_FPS + k) * HD + c]));
  out[b * HD + c] = m + bout[c];
}

// ---------------------------------------------------------------------------
// Centroid MLP path (verified rounds 1-6).
// ---------------------------------------------------------------------------
__device__ __forceinline__ void block_ln(float* h, int n, const float* __restrict__ gam,
                                         const float* __restrict__ bet, float* red,
                                         int tid, bool relu) {
  float v = (tid < n) ? h[tid] : 0.0f;
  red[tid] = v;
  __syncthreads();
  for (int s = 128; s > 0; s >>= 1) { if (tid < s) red[tid] += red[tid + s]; __syncthreads(); }
  float mean = red[0] / n;
  __syncthreads();
  float d = (tid < n) ? (h[tid] - mean) : 0.0f;
  red[tid] = d * d;
  __syncthreads();
  for (int s = 128; s > 0; s >>= 1) { if (tid < s) red[tid] += red[tid + s]; __syncthreads(); }
  float var = red[0] / n;
  __syncthreads();
  if (tid < n) {
    float o = (h[tid] - mean) / sqrtf(var + 1e-5f) * gam[tid] + bet[tid];
    if (relu) o = fmaxf(o, 0.0f);
    h[tid] = o;
  }
  __syncthreads();
}

__global__ __launch_bounds__(256) void cpathA_kernel(const float* __restrict__ cxyz,
    const float* __restrict__ w0, const float* __restrict__ b0,
    const float* __restrict__ g0, const float* __restrict__ e0,
    const float* __restrict__ w1, const float* __restrict__ b1,
    const float* __restrict__ g1, const float* __restrict__ e1,
    const float* __restrict__ w2, const float* __restrict__ b2,
    const float* __restrict__ g2, const float* __restrict__ e2,
    u32* __restrict__ cmaxU) {
  int g = blockIdx.x, b = g >> 3, tid = threadIdx.x;
  __shared__ float h[256];
  __shared__ float hb[256];
  __shared__ float red[256];
  const float* cp = cxyz + (size_t)g * 3;
  float p0 = cp[0], p1 = cp[1], p2 = cp[2];
  if (tid < 64)
    h[tid] = b0[tid] + p0 * w0[tid * 3 + 0] + p1 * w0[tid * 3 + 1] + p2 * w0[tid * 3 + 2];
  __syncthreads();
  block_ln(h, 64, g0, e0, red, tid, true);
  if (tid < 128) {
    float s = b1[tid];
    const float* wr = w1 + (size_t)tid * 64;
    for (int j = 0; j < 64; ++j) s += h[j] * wr[j];
    hb[tid] = s;
  }
  __syncthreads();
  block_ln(hb, 128, g1, e1, red, tid, true);
  {
    float s = b2[tid];
    const float* wr = w2 + (size_t)tid * 128;
    for (int j = 0; j < 128; ++j) s += hb[j] * wr[j];
    __syncthreads();
    h[tid] = s;
  }
  __syncthreads();
  block_ln(h, 256, g2, e2, red, tid, true);
  atomicMax(&cmaxU[b * 256 + tid], xf(h[tid]));
}

__global__ __launch_bounds__(256) void cpathB_kernel(const u32* __restrict__ cmaxU,
    const float* __restrict__ fw, const float* __restrict__ fb,
    const float* __restrict__ fg, const float* __restrict__ fe,
    float* __restrict__ out) {
  int b = blockIdx.x, tid = threadIdx.x;
  __shared__ float cm[256];
  __shared__ float h[256];
  __shared__ float red[256];
  cm[tid] = xinv(cmaxU[b * 256 + tid]);
  __syncthreads();
  if (tid < 128) {
    float s = fb[tid];
    const float* wr = fw + (size_t)tid * 256;
    for (int j = 0; j < 256; ++j) s += cm[j] * wr[j];
    h[tid] = s;
  }
  __syncthreads();
  block_ln(h, 128, fg, fe, red, tid, false);
  if (tid < 128) out[b * HD + tid] = h[tid];
}

// ---------------------------------------------------------------------------
extern "C" void kernel_launch(void* const* d_in, const int* in_sizes, int n_in,
                              void* d_out, int out_size, void* d_ws, size_t ws_size,
                              hipStream_t stream) {
  (void)in_sizes; (void)n_in; (void)out_size;
  const float* x          = (const float*)d_in[0];
  const float* conv_in_w  = (const float*)d_in[1];
  const float* conv_in_b  = (const float*)d_in[2];
  const float* layer_w    = (const float*)d_in[3];
  const float* layer_b    = (const float*)d_in[4];
  const float* glayer_w   = (const float*)d_in[5];
  const float* glayer_b   = (const float*)d_in[6];
  const float* conv_out_w = (const float*)d_in[7];
  const float* conv_out_b = (const float*)d_in[8];
  const float* mlp_w0 = (const float*)d_in[9];
  const float* mlp_b0 = (const float*)d_in[10];
  const float* ln0_g  = (const float*)d_in[11];
  const float* ln0_b  = (const float*)d_in[12];
  const float* mlp_w1 = (const float*)d_in[13];
  const float* mlp_b1 = (const float*)d_in[14];
  const float* ln1_g  = (const float*)d_in[15];
  const float* ln1_b  = (const float*)d_in[16];
  const float* mlp_w2 = (const float*)d_in[17];
  const float* mlp_b2 = (const float*)d_in[18];
  const float* ln2_g  = (const float*)d_in[19];
  const float* ln2_b  = (const float*)d_in[20];
  const float* fp_w   = (const float*)d_in[21];
  const float* fp_b   = (const float*)d_in[22];
  const float* fp_ln_g = (const float*)d_in[23];
  const float* fp_ln_b = (const float*)d_in[24];

  char* ws = (char*)d_ws;
  size_t off = 0;
  auto carve = [&](size_t bytes) -> void* {
    void* p = ws + off;
    off += (bytes + 255) & ~(size_t)255;
    return p;
  };
  u64* slots   = (u64*)carve(7 * B_SZ * 8);
  float* cxyz  = (float*)carve(256 * 3 * 4);
  float* grouped = (float*)carve((size_t)256 * NP * 3 * 4);
  u32* goutU   = (u32*)carve(256 * HD * 4);
  u32* tmaxU   = (u32*)carve(4 * 256 * HD * 4);
  float* gvec  = (float*)carve(257 * HD * 4);
  u32* cmaxU   = (u32*)carve(B_SZ * 256 * 4);
  short* w1h = (short*)carve(4 * 16384 * 2);
  short* w1l = (short*)carve(4 * 16384 * 2);
  short* w2h = (short*)carve(4 * 16384 * 2);
  short* w2l = (short*)carve(4 * 16384 * 2);
  short* coh = (short*)carve(65536 * 2);
  short* col_ = (short*)carve(65536 * 2);
  size_t fixed = off;

  int C = 8;
  const int cands[5] = {128, 64, 32, 16, 8};
  for (int ci = 0; ci < 5; ++ci) {
    int Cc = cands[ci];
    size_t Mp = ((size_t)(513 * Cc + 63) / 64) * 64;
    size_t need = fixed + 10 * ((Mp * HD * 2 + 255) & ~(size_t)255) + 65536;
    if (need <= ws_size) { C = Cc; break; }
  }
  int M = C * 513;
  int Mp = (int)(((size_t)(M + 63) / 64) * 64);
  int nb = Mp / 64;
  size_t planeB = (size_t)Mp * HD * 2;
  short* th = (short*)carve(planeB); short* tl = (short*)carve(planeB);
  short* fh[4]; short* fl[4];
  for (int l = 0; l < 4; ++l) { fh[l] = (short*)carve(planeB); fl[l] = (short*)carve(planeB); }

  init_all_kernel<<<(4 * 256 * HD + 255) / 256, 256, 0, stream>>>(
      (u32*)slots, tmaxU, goutU, cmaxU);

  fps_step<0><<<2048, 256, 0, stream>>>(x, slots);
  fps_step<1><<<2048, 256, 0, stream>>>(x, slots);
  fps_step<2><<<2048, 256, 0, stream>>>(x, slots);
  fps_step<3><<<2048, 256, 0, stream>>>(x, slots);
  fps_step<4><<<2048, 256, 0, stream>>>(x, slots);
  fps_step<5><<<2048, 256, 0, stream>>>(x, slots);
  fps_step<6><<<2048, 256, 0, stream>>>(x, slots);

  ballq_kernel<<<256, 1024, 0, stream>>>(x, slots, cxyz, grouped);
  wprep_kernel<<<768, 256, 0, stream>>>(layer_w, glayer_w, conv_out_w,
                                        w1h, w1l, w2h, w2l, coh, col_);

  for (int g0 = 0; g0 < 256; g0 += C) {
    // layer 0: fused conv_in + GEMM1
    u32* tmax0 = tmaxU + (size_t)0 * 256 * HD + (size_t)g0 * HD;
    mfgemm<3><<<nb, 256, 0, stream>>>(
        nullptr, nullptr, nullptr, nullptr, nullptr, nullptr, nullptr, nullptr,
        w1h, w1l, 128, layer_b,
        conv_in_w, conv_in_b, grouped + (size_t)g0 * NP * 3,
        th, tl, tmax0, M);
    gvec_kernel<<<C, HD, 0, stream>>>(tmax0, glayer_w, glayer_b, gvec);
    mfgemm<1><<<nb, 256, 0, stream>>>(
        th, tl, th, tl, th, tl, th, tl,
        w2h, w2l, 128, gvec, nullptr, nullptr, nullptr,
        fh[0], fl[0], nullptr, M);
    for (int l = 1; l < 4; ++l) {
      u32* tmaxL = tmaxU + (size_t)l * 256 * HD + (size_t)g0 * HD;
      mfgemm<0><<<nb, 256, 0, stream>>>(
          fh[l-1], fl[l-1], fh[l-1], fl[l-1], fh[l-1], fl[l-1], fh[l-1], fl[l-1],
          w1h + (size_t)l * 16384, w1l + (size_t)l * 16384, 128,
          layer_b + l * HD, nullptr, nullptr, nullptr,
          th, tl, tmaxL, M);
      gvec_kernel<<<C, HD, 0, stream>>>(tmaxL, glayer_w + (size_t)l * HD * 2 * HD,
                                        glayer_b + l * HD, gvec);
      mfgemm<1><<<nb, 256, 0, stream>>>(
          th, tl, th, tl, th, tl, th, tl,
          w2h + (size_t)l * 16384, w2l + (size_t)l * 16384, 128,
          gvec, nullptr, nullptr, nullptr,
          fh[l], fl[l], nullptr, M);
    }
    mfgemm<2><<<nb, 256, 0, stream>>>(
        fh[0], fl[0], fh[1], fl[1], fh[2], fl[2], fh[3], fl[3],
        coh, col_, 512, nullptr, nullptr, nullptr, nullptr,
        nullptr, nullptr, goutU + (size_t)g0 * HD, M);
  }
  batchmax_kernel<<<B_SZ, HD, 0, stream>>>(goutU, conv_out_b, (float*)d_out);
  cpathA_kernel<<<256, 256, 0, stream>>>(cxyz,
      mlp_w0, mlp_b0, ln0_g, ln0_b,
      mlp_w1, mlp_b1, ln1_g, ln1_b,
      mlp_w2, mlp_b2, ln2_g, ln2_b, cmaxU);
  cpathB_kernel<<<B_SZ, 256, 0, stream>>>(cmaxU, fp_w, fp_b, fp_ln_g, fp_ln_b,
                                          (float*)d_out + B_SZ * HD);
}